// Round 10
// baseline (982.586 us; speedup 1.0000x reference)
//
#include <hip/hip_runtime.h>
#include <hip/hip_bf16.h>

#define DIV_UP(a,b) (((a)+(b)-1)/(b))

typedef __attribute__((ext_vector_type(8))) short bf16x8;
typedef __attribute__((ext_vector_type(4))) float f32x4;

__device__ __forceinline__ float silu_f(float x) {
    return x / (1.0f + __expf(-x));
}
__device__ __forceinline__ unsigned short f2bf(float x) {
    __hip_bfloat16 h = __float2bfloat16(x);
    return *reinterpret_cast<unsigned short*>(&h);
}
__device__ __forceinline__ float bf2f(unsigned short u) {
    unsigned int v = (unsigned int)u << 16;
    return __uint_as_float(v);
}
__device__ __forceinline__ void split_bf(float x, unsigned short& hi, unsigned short& lo) {
    hi = f2bf(x);
    lo = f2bf(x - bf2f(hi));
}
__device__ __forceinline__ bf16x8 pack8(unsigned int w0, unsigned int w1,
                                        unsigned int w2, unsigned int w3) {
    union { unsigned int u[4]; bf16x8 v; } t;
    t.u[0] = w0; t.u[1] = w1; t.u[2] = w2; t.u[3] = w3;
    return t.v;
}

#define WSLOT 16384    // 128*128 bf16 per K=128 weight slot
#define WSLOT2 27648   // 144*192 bf16 per sct weight slot

// ---------------------------------------------------------------------------
// Weight prep (K=128 MLPs): f32 [128][128] -> bf16 hi/lo, transposed.
// ---------------------------------------------------------------------------
__global__ __launch_bounds__(256) void prep_weights_kernel(
    const float* __restrict__ msgW1, const float* __restrict__ msgW2,
    const float* __restrict__ denseW1, const float* __restrict__ denseW2,
    unsigned short* __restrict__ WB)
{
    int slot = blockIdx.y;
    int kind = slot / 3, conv = slot % 3;
    const float* base;
    switch (kind) {
        case 0: base = msgW1; break;
        case 1: base = msgW2; break;
        case 2: base = denseW1; break;
        default: base = denseW2; break;
    }
    const float* W = base + (size_t)conv * 128 * 128;
    int idx = blockIdx.x * 256 + threadIdx.x;
    if (idx >= 16384) return;
    int c = idx >> 7, k = idx & 127;
    float val = W[(size_t)k * 128 + c];
    unsigned short hi, lo;
    split_bf(val, hi, lo);
    WB[(size_t)(2 * slot) * WSLOT + idx]     = hi;
    WB[(size_t)(2 * slot + 1) * WSLOT + idx] = lo;
}

// ---------------------------------------------------------------------------
// Weight prep (sct K=138): f32 [138][138] -> bf16 hi/lo, transposed, padded
// to [144][192].  slot = kind*3+conv, kind 0=W1, 1=W2.
// ---------------------------------------------------------------------------
__global__ __launch_bounds__(256) void prep_sct_kernel(
    const float* __restrict__ sctW1, const float* __restrict__ sctW2,
    unsigned short* __restrict__ WB2)
{
    int slot = blockIdx.y;
    int kind = slot / 3, conv = slot % 3;
    const float* base = (kind == 0) ? sctW1 : sctW2;
    const float* W = base + (size_t)conv * 138 * 138;
    int idx = blockIdx.x * 256 + threadIdx.x;
    if (idx >= WSLOT2) return;
    int c = idx / 192, k = idx - c * 192;
    float val = (c < 138 && k < 138) ? W[(size_t)k * 138 + c] : 0.0f;
    unsigned short hi, lo;
    split_bf(val, hi, lo);
    WB2[(size_t)(2 * slot) * WSLOT2 + idx]     = hi;
    WB2[(size_t)(2 * slot + 1) * WSLOT2 + idx] = lo;
}

// ---------------------------------------------------------------------------
// CSR build: histogram -> single-block scan with PER-NODE PADDING to x32.
// ---------------------------------------------------------------------------
__global__ __launch_bounds__(256) void hist_kernel(
    const int* __restrict__ nbr, int* __restrict__ counts, int E)
{
    int e = blockIdx.x * 256 + threadIdx.x;
    if (e < E) atomicAdd(&counts[nbr[2 * e]], 1);
}

__global__ __launch_bounds__(1024) void scan_kernel(
    const int* __restrict__ counts, int* __restrict__ peptr, int N)
{
    __shared__ int part[1024];
    const int t = threadIdx.x;
    const int chunk = DIV_UP(N, 1024);
    int s = 0;
    for (int c = 0; c < chunk; ++c) {
        int idx = t * chunk + c;
        if (idx < N) s += (counts[idx] + 31) & ~31;
    }
    part[t] = s;
    __syncthreads();
    for (int off = 1; off < 1024; off <<= 1) {
        int v = (t >= off) ? part[t - off] : 0;
        __syncthreads();
        part[t] += v;
        __syncthreads();
    }
    int pre = (t > 0) ? part[t - 1] : 0;
    for (int c = 0; c < chunk; ++c) {
        int idx = t * chunk + c;
        if (idx < N) { peptr[idx] = pre; pre += (counts[idx] + 31) & ~31; }
    }
    if (t == 1023) peptr[N] = part[1023];
}

// ---------------------------------------------------------------------------
// Fused edge geometry + padded-CSR scatter (contiguous 32B rbf records).
// ---------------------------------------------------------------------------
__global__ __launch_bounds__(256) void geom_scatter_kernel(
    const int* __restrict__ nbr, const float* __restrict__ xyz,
    const int* __restrict__ peptr, int* __restrict__ cursor,
    unsigned short* __restrict__ rbfs, unsigned short* __restrict__ envs,
    int* __restrict__ js, int E)
{
    int e = blockIdx.x * 256 + threadIdx.x;
    if (e >= E) return;
    int i = nbr[2 * e], j = nbr[2 * e + 1];
    float dx = xyz[3 * j + 0] - xyz[3 * i + 0];
    float dy = xyz[3 * j + 1] - xyz[3 * i + 1];
    float dz = xyz[3 * j + 2] - xyz[3 * i + 2];
    float dist = sqrtf(dx * dx + dy * dy + dz * dz);
    float x = dist * 0.3141592653589793f;   // pi/CUTOFF
    float s, c;
    __sincosf(x, &s, &c);
    float env = (dist < 10.0f) ? 0.5f * (c + 1.0f) : 0.0f;
    float inv_env = env / dist;
    float two_c = 2.0f * c;
    float sm1 = 0.0f, s0 = s;
    __align__(16) unsigned short ob[16];
    #pragma unroll
    for (int k = 0; k < 16; ++k) {
        ob[k] = f2bf(s0 * inv_env);
        float s1 = two_c * s0 - sm1;
        sm1 = s0; s0 = s1;
    }
    int p = peptr[i] + atomicAdd(&cursor[i], 1);
    uint4* rp = (uint4*)(rbfs + (size_t)p * 16);
    rp[0] = *(const uint4*)&ob[0];
    rp[1] = *(const uint4*)&ob[8];
    envs[p] = f2bf(env);
    js[p] = j;
}

// ---------------------------------------------------------------------------
// S0 = concat(S[N,124], res_embed[cg_z][N,4])  -> [N,128]
// ---------------------------------------------------------------------------
__global__ __launch_bounds__(256) void concat_s_kernel(
    const float* __restrict__ S, const float* __restrict__ res_embed,
    const int* __restrict__ z, float* __restrict__ S0, int N)
{
    int idx = blockIdx.x * 256 + threadIdx.x;
    if (idx >= N * 128) return;
    int n = idx >> 7, c = idx & 127;
    float val = (c < 124) ? S[n * 124 + c] : res_embed[z[n] * 4 + (c - 124)];
    S0[idx] = val;
}

// ---------------------------------------------------------------------------
// scS = concat(S0[N,128], scA[N,10]) -> [N,140] (2 pad zeros)
// ---------------------------------------------------------------------------
__global__ __launch_bounds__(256) void concat_sc_kernel(
    const float* __restrict__ S0, const float* __restrict__ scA,
    float* __restrict__ scS, int N)
{
    int idx = blockIdx.x * 256 + threadIdx.x;
    if (idx >= N * 140) return;
    int n = idx / 140, c = idx - n * 140;
    float val = 0.0f;
    if (c < 128)       val = S0[n * 128 + c];
    else if (c < 138)  val = scA[n * 10 + (c - 128)];
    scS[idx] = val;
}

// ---------------------------------------------------------------------------
// Split-bf16 MFMA two-stage MLP, K=128, LDS 56 KB (r6-proven, untouched).
// ---------------------------------------------------------------------------
template<int MT, bool PREACT, bool RESID, typename OutT>
__global__ __launch_bounds__(256) void mlp2_mfma_kernel(
    const float* __restrict__ X,
    const unsigned short* __restrict__ W1hi, const unsigned short* __restrict__ W1lo,
    const float* __restrict__ b1,
    const unsigned short* __restrict__ W2hi, const unsigned short* __restrict__ W2lo,
    const float* __restrict__ b2,
    OutT* __restrict__ Y, int nrows)
{
    constexpr int RB   = MT / 16;
    constexpr int ROWB = 256;
    __shared__ __align__(16) unsigned short XHhi[MT * 128];
    __shared__ __align__(16) unsigned short XHlo[MT * 128];
    __shared__ __align__(16) unsigned short WS[128 * 128];

    const int tid  = threadIdx.x;
    const int wave = tid >> 6;
    const int lane = tid & 63;
    const int l15  = lane & 15;
    const int kg   = lane >> 4;
    const int row0 = blockIdx.x * MT;

    for (int idx = tid; idx < MT * 32; idx += 256) {
        int r = idx >> 5, q = idx & 31;
        int gr = row0 + r;
        float4 xv = make_float4(0.f, 0.f, 0.f, 0.f);
        if (gr < nrows) xv = *(const float4*)(X + (size_t)gr * 128 + 4 * q);
        if (PREACT) { xv.x = silu_f(xv.x); xv.y = silu_f(xv.y);
                      xv.z = silu_f(xv.z); xv.w = silu_f(xv.w); }
        ushort4 h, l;
        split_bf(xv.x, h.x, l.x); split_bf(xv.y, h.y, l.y);
        split_bf(xv.z, h.z, l.z); split_bf(xv.w, h.w, l.w);
        int off = (8 * q) ^ ((r & 7) << 4);
        *(ushort4*)((char*)XHhi + r * ROWB + off) = h;
        *(ushort4*)((char*)XHlo + r * ROWB + off) = l;
    }

    f32x4 acc[RB][2];

    #define STAGE_W(WPTR)                                                       \
        for (int idx = tid; idx < 2048; idx += 256) {                           \
            int r = idx >> 4;                                                   \
            int byt = (idx & 15) * 16;                                          \
            *(uint4*)((char*)WS + r * ROWB + (byt ^ ((r & 7) << 4))) =          \
                *(const uint4*)((WPTR) + (size_t)idx * 8);                      \
        }

    #define PASS(WITH_LO)                                                       \
        _Pragma("unroll")                                                       \
        for (int kk = 0; kk < 4; ++kk) {                                        \
            const int kbyte = kk * 64 + kg * 16;                                \
            bf16x8 ah[RB], al[RB];                                              \
            _Pragma("unroll")                                                   \
            for (int rb = 0; rb < RB; ++rb) {                                   \
                int r = 16 * rb + l15;                                          \
                int off = kbyte ^ ((r & 7) << 4);                               \
                ah[rb] = *(const bf16x8*)((const char*)XHhi + r * ROWB + off);  \
                if (WITH_LO)                                                    \
                    al[rb] = *(const bf16x8*)((const char*)XHlo + r * ROWB + off); \
            }                                                                   \
            _Pragma("unroll")                                                   \
            for (int cbi = 0; cbi < 2; ++cbi) {                                 \
                int rw = 16 * (wave + 4 * cbi) + l15;                           \
                int offw = kbyte ^ ((rw & 7) << 4);                             \
                bf16x8 bw = *(const bf16x8*)((const char*)WS + rw * ROWB + offw); \
                _Pragma("unroll")                                               \
                for (int rb = 0; rb < RB; ++rb) {                               \
                    f32x4 t = acc[rb][cbi];                                     \
                    t = __builtin_amdgcn_mfma_f32_16x16x32_bf16(ah[rb], bw, t, 0, 0, 0); \
                    if (WITH_LO)                                                \
                        t = __builtin_amdgcn_mfma_f32_16x16x32_bf16(al[rb], bw, t, 0, 0, 0); \
                    acc[rb][cbi] = t;                                           \
                }                                                               \
            }                                                                   \
        }

    #pragma unroll
    for (int a = 0; a < RB; ++a) { acc[a][0] = (f32x4){0,0,0,0}; acc[a][1] = (f32x4){0,0,0,0}; }
    STAGE_W(W1hi)
    __syncthreads();
    PASS(true)
    __syncthreads();
    STAGE_W(W1lo)
    __syncthreads();
    PASS(false)
    __syncthreads();

    #pragma unroll
    for (int cbi = 0; cbi < 2; ++cbi) {
        int col = 16 * (wave + 4 * cbi) + l15;
        float b1v = b1[col];
        #pragma unroll
        for (int rb = 0; rb < RB; ++rb)
            #pragma unroll
            for (int i = 0; i < 4; ++i) {
                int r = 16 * rb + kg * 4 + i;
                float h = silu_f(acc[rb][cbi][i] + b1v);
                unsigned short hh, hl;
                split_bf(h, hh, hl);
                int off = (2 * col) ^ ((r & 7) << 4);
                *(unsigned short*)((char*)XHhi + r * ROWB + off) = hh;
                *(unsigned short*)((char*)XHlo + r * ROWB + off) = hl;
            }
    }
    #pragma unroll
    for (int a = 0; a < RB; ++a) { acc[a][0] = (f32x4){0,0,0,0}; acc[a][1] = (f32x4){0,0,0,0}; }
    STAGE_W(W2hi)
    __syncthreads();
    PASS(true)
    __syncthreads();
    STAGE_W(W2lo)
    __syncthreads();
    PASS(false)
    #undef PASS
    #undef STAGE_W

    #pragma unroll
    for (int cbi = 0; cbi < 2; ++cbi) {
        int col = 16 * (wave + 4 * cbi) + l15;
        float b2v = b2[col];
        #pragma unroll
        for (int rb = 0; rb < RB; ++rb)
            #pragma unroll
            for (int i = 0; i < 4; ++i) {
                int gr = row0 + 16 * rb + kg * 4 + i;
                if (gr < nrows) {
                    size_t off = (size_t)gr * 128 + col;
                    float val = acc[rb][cbi][i] + b2v;
                    if (RESID) val += (float)Y[off];
                    if constexpr (sizeof(OutT) == 2)
                        Y[off] = __float2bfloat16(val);
                    else
                        Y[off] = val;
                }
            }
    }
}

// ---------------------------------------------------------------------------
// Split-bf16 MFMA residual MLP for K=138 (sct layers).  KP=192 (two 96-col
// halves streamed through one WS buffer), NP=144, MT=32.  LDS = 60 KB.
//   scS (+=) silu( silu(scS) @ W1 + b1 ) @ W2 + b2 ;  ld = 140
// ---------------------------------------------------------------------------
__global__ __launch_bounds__(256) void sct_mfma_kernel(
    const float* __restrict__ X,
    const unsigned short* __restrict__ W1hi, const unsigned short* __restrict__ W1lo,
    const float* __restrict__ b1,
    const unsigned short* __restrict__ W2hi, const unsigned short* __restrict__ W2lo,
    const float* __restrict__ b2,
    float* __restrict__ Y, int nrows)
{
    constexpr int MT = 32, KP = 192, NP = 144;
    constexpr int RXB = 384;   // XH row bytes (192 bf16)
    constexpr int RWB = 256;   // WS row bytes (128 bf16; 96 used + swizzle room)
    __shared__ __align__(16) unsigned short XHhi[MT * KP];   // 12288 B
    __shared__ __align__(16) unsigned short XHlo[MT * KP];   // 12288 B
    __shared__ __align__(16) unsigned short WS[NP * 128];    // 36864 B

    const int tid  = threadIdx.x;
    const int wave = tid >> 6;
    const int lane = tid & 63;
    const int l15  = lane & 15;
    const int kg   = lane >> 4;
    const int row0 = blockIdx.x * MT;

    // ---- stage X (pre-activated), zero-padded to KP ----
    for (int idx = tid; idx < MT * KP; idx += 256) {
        int r = idx / KP, c = idx - r * KP;
        int gr = row0 + r;
        float x = (gr < nrows && c < 138) ? silu_f(X[(size_t)gr * 140 + c]) : 0.0f;
        unsigned short h, l;
        split_bf(x, h, l);
        int off = (2 * c) ^ ((r & 7) << 4);
        *(unsigned short*)((char*)XHhi + r * RXB + off) = h;
        *(unsigned short*)((char*)XHlo + r * RXB + off) = l;
    }

    f32x4 acc[2][3];

    // stage one 96-col half of a W panel ([NP][192] source) into WS
    #define STAGE_WH(WPTR, H)                                                   \
        for (int idx = tid; idx < NP * 12; idx += 256) {                        \
            int r = idx / 12, ch = idx - r * 12;                                \
            *(uint4*)((char*)WS + r * RWB + ((ch * 16) ^ ((r & 7) << 4))) =     \
                *(const uint4*)((WPTR) + (size_t)r * 192 + (H) * 96 + ch * 8);  \
        }

    #define PASSH(H, WITH_LO)                                                   \
        _Pragma("unroll")                                                       \
        for (int kk = 0; kk < 3; ++kk) {                                        \
            const int kbx = (H) * 192 + kk * 64 + kg * 16;                      \
            const int kbw = kk * 64 + kg * 16;                                  \
            bf16x8 ah[2], al[2];                                                \
            _Pragma("unroll")                                                   \
            for (int rb = 0; rb < 2; ++rb) {                                    \
                int r = 16 * rb + l15;                                          \
                int off = kbx ^ ((r & 7) << 4);                                 \
                ah[rb] = *(const bf16x8*)((const char*)XHhi + r * RXB + off);   \
                if (WITH_LO)                                                    \
                    al[rb] = *(const bf16x8*)((const char*)XHlo + r * RXB + off); \
            }                                                                   \
            _Pragma("unroll")                                                   \
            for (int cbi = 0; cbi < 3; ++cbi) {                                 \
                int cb = wave + 4 * cbi;                                        \
                if (cb < 9) {                                                   \
                    int rw = 16 * cb + l15;                                     \
                    int offw = kbw ^ ((rw & 7) << 4);                           \
                    bf16x8 bw = *(const bf16x8*)((const char*)WS + rw * RWB + offw); \
                    _Pragma("unroll")                                           \
                    for (int rb = 0; rb < 2; ++rb) {                            \
                        f32x4 t = acc[rb][cbi];                                 \
                        t = __builtin_amdgcn_mfma_f32_16x16x32_bf16(ah[rb], bw, t, 0, 0, 0); \
                        if (WITH_LO)                                            \
                            t = __builtin_amdgcn_mfma_f32_16x16x32_bf16(al[rb], bw, t, 0, 0, 0); \
                        acc[rb][cbi] = t;                                       \
                    }                                                           \
                }                                                               \
            }                                                                   \
        }

    #define GEMM_STAGE(WHI, WLO)                                                \
        STAGE_WH(WHI, 0) __syncthreads(); PASSH(0, true)  __syncthreads();      \
        STAGE_WH(WHI, 1) __syncthreads(); PASSH(1, true)  __syncthreads();      \
        STAGE_WH(WLO, 0) __syncthreads(); PASSH(0, false) __syncthreads();      \
        STAGE_WH(WLO, 1) __syncthreads(); PASSH(1, false) __syncthreads();

    // ================= stage 1: silu(X) @ W1 =================
    #pragma unroll
    for (int a = 0; a < 2; ++a)
        #pragma unroll
        for (int b = 0; b < 3; ++b) acc[a][b] = (f32x4){0,0,0,0};
    GEMM_STAGE(W1hi, W1lo)

    // ---- H = silu(acc + b1) -> XH (cols >=138 zeroed; 144..191 keep X zeros)
    #pragma unroll
    for (int cbi = 0; cbi < 3; ++cbi) {
        int cb = wave + 4 * cbi;
        if (cb < 9) {
            int col = 16 * cb + l15;
            float b1v = (col < 138) ? b1[col] : 0.0f;
            #pragma unroll
            for (int rb = 0; rb < 2; ++rb)
                #pragma unroll
                for (int i = 0; i < 4; ++i) {
                    int r = 16 * rb + kg * 4 + i;
                    float h = (col < 138) ? silu_f(acc[rb][cbi][i] + b1v) : 0.0f;
                    unsigned short hh, hl;
                    split_bf(h, hh, hl);
                    int off = (2 * col) ^ ((r & 7) << 4);
                    *(unsigned short*)((char*)XHhi + r * RXB + off) = hh;
                    *(unsigned short*)((char*)XHlo + r * RXB + off) = hl;
                }
        }
    }
    __syncthreads();

    // ================= stage 2: H @ W2 =================
    #pragma unroll
    for (int a = 0; a < 2; ++a)
        #pragma unroll
        for (int b = 0; b < 3; ++b) acc[a][b] = (f32x4){0,0,0,0};
    GEMM_STAGE(W2hi, W2lo)
    #undef GEMM_STAGE
    #undef PASSH
    #undef STAGE_WH

    // ---- epilogue: Y += acc + b2 (residual) ----
    #pragma unroll
    for (int cbi = 0; cbi < 3; ++cbi) {
        int cb = wave + 4 * cbi;
        if (cb < 9) {
            int col = 16 * cb + l15;
            if (col < 138) {
                float b2v = b2[col];
                #pragma unroll
                for (int rb = 0; rb < 2; ++rb)
                    #pragma unroll
                    for (int i = 0; i < 4; ++i) {
                        int gr = row0 + 16 * rb + kg * 4 + i;
                        if (gr < nrows) {
                            size_t off = (size_t)gr * 140 + col;
                            Y[off] = Y[off] + acc[rb][cbi][i] + b2v;
                        }
                    }
            }
        }
    }
}

// ---------------------------------------------------------------------------
// Register-direct MFMA gather, TWO nodes per wave (ILP over the serial
// peptr->js->phi latency chains).  Math identical to r8 (proven):
//   T = rbf^T(16x32) @ Phi(32x128) per node;
//   v[n][c] = sum_k dW[k][c]*T[k][c] + db[c]*T_env[c]
// env-MFMA folded into per-chunk zero-C temp + scalar accumulate.
// ---------------------------------------------------------------------------
__global__ __launch_bounds__(256) void gather_mfma_kernel(
    const int* __restrict__ peptr, const int* __restrict__ counts,
    const unsigned short* __restrict__ rbfs,   // [EPAD][16] bf16
    const unsigned short* __restrict__ envs,   // [EPAD] bf16
    const int* __restrict__ js,                // [EPAD]
    const unsigned short* __restrict__ phi,    // [N][128] bf16
    const float* __restrict__ distW, const float* __restrict__ distb,
    float* __restrict__ v, int N)
{
    const int wave = threadIdx.x >> 6;
    const int lane = threadIdx.x & 63;
    const int n0 = (blockIdx.x * 4 + wave) * 2;
    if (n0 >= N) return;
    const int n1ok = (n0 + 1 < N);
    const int l15 = lane & 15;
    const int lg  = lane >> 4;

    f32x4 acc0[8], acc1[8];
    float eac0[8], eac1[8];
    #pragma unroll
    for (int cb = 0; cb < 8; ++cb) {
        acc0[cb] = (f32x4){0,0,0,0}; acc1[cb] = (f32x4){0,0,0,0};
        eac0[cb] = 0.f; eac1[cb] = 0.f;
    }

    const int p0 = peptr[n0], e0 = peptr[n0 + 1];
    const int d0 = counts[n0];
    const int p1 = e0;
    const int e1 = n1ok ? peptr[n0 + 2] : e0;
    const int d1 = n1ok ? counts[n0 + 1] : 0;

    int t0 = p0, t1 = p1;
    while (t0 < e0 || t1 < e1) {
        const bool a0 = t0 < e0, a1 = t1 < e1;
        const int rem0 = a0 ? (d0 - (t0 - p0) - 8 * lg) : 0;
        const int rem1 = a1 ? (d1 - (t1 - p1) - 8 * lg) : 0;

        // ---- slot 0 loads ----
        const int* jb0 = js + t0 + 8 * lg;
        int jr0[8];
        #pragma unroll
        for (int i = 0; i < 8; ++i) jr0[i] = (i < rem0) ? jb0[i] : 0;
        const unsigned short* ab0 = rbfs + (size_t)(t0 + 8 * lg) * 16 + l15;
        unsigned int aw0[4];
        #pragma unroll
        for (int w = 0; w < 4; ++w) {
            unsigned int lo = (2 * w     < rem0) ? (unsigned int)ab0[(2 * w) * 16]     : 0u;
            unsigned int hi = (2 * w + 1 < rem0) ? (unsigned int)ab0[(2 * w + 1) * 16] : 0u;
            aw0[w] = lo | (hi << 16);
        }
        bf16x8 af0 = pack8(aw0[0], aw0[1], aw0[2], aw0[3]);
        unsigned int ew0[4] = {0u, 0u, 0u, 0u};
        if (l15 == 0) {
            const unsigned short* eb = envs + t0 + 8 * lg;
            #pragma unroll
            for (int w = 0; w < 4; ++w) {
                unsigned int lo = (2 * w     < rem0) ? (unsigned int)eb[2 * w]     : 0u;
                unsigned int hi = (2 * w + 1 < rem0) ? (unsigned int)eb[2 * w + 1] : 0u;
                ew0[w] = lo | (hi << 16);
            }
        }
        bf16x8 a2f0 = pack8(ew0[0], ew0[1], ew0[2], ew0[3]);

        // ---- slot 1 loads ----
        const int* jb1 = js + t1 + 8 * lg;
        int jr1[8];
        #pragma unroll
        for (int i = 0; i < 8; ++i) jr1[i] = (i < rem1) ? jb1[i] : 0;
        const unsigned short* ab1 = rbfs + (size_t)(t1 + 8 * lg) * 16 + l15;
        unsigned int aw1[4];
        #pragma unroll
        for (int w = 0; w < 4; ++w) {
            unsigned int lo = (2 * w     < rem1) ? (unsigned int)ab1[(2 * w) * 16]     : 0u;
            unsigned int hi = (2 * w + 1 < rem1) ? (unsigned int)ab1[(2 * w + 1) * 16] : 0u;
            aw1[w] = lo | (hi << 16);
        }
        bf16x8 af1 = pack8(aw1[0], aw1[1], aw1[2], aw1[3]);
        unsigned int ew1[4] = {0u, 0u, 0u, 0u};
        if (l15 == 0) {
            const unsigned short* eb = envs + t1 + 8 * lg;
            #pragma unroll
            for (int w = 0; w < 4; ++w) {
                unsigned int lo = (2 * w     < rem1) ? (unsigned int)eb[2 * w]     : 0u;
                unsigned int hi = (2 * w + 1 < rem1) ? (unsigned int)eb[2 * w + 1] : 0u;
                ew1[w] = lo | (hi << 16);
            }
        }
        bf16x8 a2f1 = pack8(ew1[0], ew1[1], ew1[2], ew1[3]);

        const unsigned short* q0[8];
        const unsigned short* q1[8];
        #pragma unroll
        for (int i = 0; i < 8; ++i) {
            q0[i] = phi + (size_t)jr0[i] * 128 + l15;
            q1[i] = phi + (size_t)jr1[i] * 128 + l15;
        }

        // ---- interleaved B-frag loads + MFMAs ----
        #pragma unroll
        for (int cb = 0; cb < 8; ++cb) {
            const int o = cb * 16;
            bf16x8 bf0 = pack8(
                (unsigned int)q0[0][o] | ((unsigned int)q0[1][o] << 16),
                (unsigned int)q0[2][o] | ((unsigned int)q0[3][o] << 16),
                (unsigned int)q0[4][o] | ((unsigned int)q0[5][o] << 16),
                (unsigned int)q0[6][o] | ((unsigned int)q0[7][o] << 16));
            bf16x8 bf1 = pack8(
                (unsigned int)q1[0][o] | ((unsigned int)q1[1][o] << 16),
                (unsigned int)q1[2][o] | ((unsigned int)q1[3][o] << 16),
                (unsigned int)q1[4][o] | ((unsigned int)q1[5][o] << 16),
                (unsigned int)q1[6][o] | ((unsigned int)q1[7][o] << 16));
            f32x4 z0 = (f32x4){0,0,0,0};
            f32x4 z1 = (f32x4){0,0,0,0};
            acc0[cb] = __builtin_amdgcn_mfma_f32_16x16x32_bf16(af0, bf0, acc0[cb], 0, 0, 0);
            acc1[cb] = __builtin_amdgcn_mfma_f32_16x16x32_bf16(af1, bf1, acc1[cb], 0, 0, 0);
            z0 = __builtin_amdgcn_mfma_f32_16x16x32_bf16(a2f0, bf0, z0, 0, 0, 0);
            z1 = __builtin_amdgcn_mfma_f32_16x16x32_bf16(a2f1, bf1, z1, 0, 0, 0);
            eac0[cb] += z0[0];
            eac1[cb] += z1[0];
        }
        if (a0) t0 += 32;
        if (a1) t1 += 32;
    }

    // ---- epilogue x2: dot with dW rows, add db*T_env, lane-group reduce ----
    #pragma unroll
    for (int cb = 0; cb < 8; ++cb) {
        int col = cb * 16 + l15;
        float w0 = distW[(lg * 4 + 0) * 128 + col];
        float w1 = distW[(lg * 4 + 1) * 128 + col];
        float w2 = distW[(lg * 4 + 2) * 128 + col];
        float w3 = distW[(lg * 4 + 3) * 128 + col];
        float pa = acc0[cb][0] * w0;
        pa = fmaf(acc0[cb][1], w1, pa);
        pa = fmaf(acc0[cb][2], w2, pa);
        pa = fmaf(acc0[cb][3], w3, pa);
        float pb = acc1[cb][0] * w0;
        pb = fmaf(acc1[cb][1], w1, pb);
        pb = fmaf(acc1[cb][2], w2, pb);
        pb = fmaf(acc1[cb][3], w3, pb);
        if (lg == 0) {
            float dbv = distb[col];
            pa = fmaf(eac0[cb], dbv, pa);
            pb = fmaf(eac1[cb], dbv, pb);
        }
        pa += __shfl_xor(pa, 16, 64);
        pa += __shfl_xor(pa, 32, 64);
        pb += __shfl_xor(pb, 16, 64);
        pb += __shfl_xor(pb, 32, 64);
        if (lane < 16) {
            v[(size_t)n0 * 128 + col] = pa;
            if (n1ok) v[(size_t)(n0 + 1) * 128 + col] = pb;
        }
    }
}

// ---------------------------------------------------------------------------
// Small head: out = silu( silu(x) @ W1 + b1 ) @ W2 + b2   (final linear)
// ---------------------------------------------------------------------------
template<int M>
__global__ __launch_bounds__(256) void head_kernel(
    const float* __restrict__ X, int ldX, int K1,
    const float* __restrict__ X2, int ldX2, int K2,
    const float* __restrict__ W1, const float* __restrict__ b1,
    const float* __restrict__ W2, const float* __restrict__ b2,
    float* __restrict__ out, int ldOut, int nrows)
{
    const int wid = threadIdx.x >> 6;
    const int lane = threadIdx.x & 63;
    const int n = blockIdx.x * 4 + wid;
    if (n >= nrows) return;
    const int K = K1 + K2;
    float sx[3];
    #pragma unroll
    for (int t = 0; t < 3; ++t) {
        int k = lane + 64 * t;
        float v = 0.0f;
        if (k < K1) v = X[(size_t)n * ldX + k];
        else if (k < K) v = X2[(size_t)n * ldX2 + (k - K1)];
        sx[t] = (k < K) ? silu_f(v) : 0.0f;
    }
    float acc[M];
    #pragma unroll
    for (int m = 0; m < M; ++m) {
        float a = 0.0f;
        #pragma unroll
        for (int t = 0; t < 3; ++t) {
            int k = lane + 64 * t;
            if (k < K) a = fmaf(sx[t], W1[k * M + m], a);
        }
        acc[m] = a;
    }
    #pragma unroll
    for (int m = 0; m < M; ++m) {
        #pragma unroll
        for (int off = 32; off > 0; off >>= 1)
            acc[m] += __shfl_xor(acc[m], off, 64);
    }
    float tm[M];
    #pragma unroll
    for (int m = 0; m < M; ++m) tm[m] = silu_f(acc[m] + b1[m]);
    if (lane < M) {
        float o = b2[lane];
        #pragma unroll
        for (int m = 0; m < M; ++m) o = fmaf(tm[m], W2[m * M + lane], o);
        out[(size_t)n * ldOut + lane] = o;
    }
}

// ---------------------------------------------------------------------------
// Output assembly: out[N][13][3]
// ---------------------------------------------------------------------------
__global__ __launch_bounds__(256) void assemble_kernel(
    const int* __restrict__ z,
    const float* __restrict__ bbde, const float* __restrict__ scde,
    const float* __restrict__ bbA, const float* __restrict__ bbT,
    const float* __restrict__ scA, const float* __restrict__ scT,
    float* __restrict__ out, int N)
{
    int idx = blockIdx.x * 256 + threadIdx.x;
    if (idx >= N * 39) return;
    int n = idx / 39;
    int s = idx - n * 39;
    int row = s / 3;
    int col = s - row * 3;
    float val;
    if (row < 3) {
        if (col == 0)      val = bbde[z[n] * 3 + row];
        else if (col == 1) val = bbA[n * 3 + row];
        else               val = bbT[n * 3 + row];
    } else {
        int r = row - 3;
        if (col == 0)      val = scde[z[n] * 10 + r];
        else if (col == 1) val = scA[n * 10 + r];
        else               val = scT[n * 10 + r];
    }
    out[idx] = val;
}

extern "C" void kernel_launch(void* const* d_in, const int* in_sizes, int n_in,
                              void* d_out, int out_size, void* d_ws, size_t ws_size,
                              hipStream_t stream)
{
    const int*   cg_z        = (const int*)d_in[0];
    const float* cg_xyz      = (const float*)d_in[1];
    const int*   nbr         = (const int*)d_in[2];
    // d_in[3] = mapping (unused by reference)
    const float* S_in        = (const float*)d_in[4];
    const float* res_embed   = (const float*)d_in[5];
    const float* msg_W1      = (const float*)d_in[6];
    const float* msg_b1      = (const float*)d_in[7];
    const float* msg_W2      = (const float*)d_in[8];
    const float* msg_b2      = (const float*)d_in[9];
    const float* dist_W      = (const float*)d_in[10];
    const float* dist_b      = (const float*)d_in[11];
    const float* dense_W1    = (const float*)d_in[12];
    const float* dense_b1    = (const float*)d_in[13];
    const float* dense_W2    = (const float*)d_in[14];
    const float* dense_b2    = (const float*)d_in[15];
    const float* bb_dist_emb = (const float*)d_in[16];
    const float* sc_dist_emb = (const float*)d_in[17];
    const float* bba_W1      = (const float*)d_in[18];
    const float* bba_b1      = (const float*)d_in[19];
    const float* bba_W2      = (const float*)d_in[20];
    const float* bba_b2      = (const float*)d_in[21];
    const float* sca_W1      = (const float*)d_in[22];
    const float* sca_b1      = (const float*)d_in[23];
    const float* sca_W2      = (const float*)d_in[24];
    const float* sca_b2      = (const float*)d_in[25];
    const float* bbt_W1      = (const float*)d_in[26];
    const float* bbt_b1      = (const float*)d_in[27];
    const float* bbt_W2      = (const float*)d_in[28];
    const float* bbt_b2      = (const float*)d_in[29];
    const float* sct_W1      = (const float*)d_in[30];
    const float* sct_b1      = (const float*)d_in[31];
    const float* sct_W2      = (const float*)d_in[32];
    const float* sct_b2      = (const float*)d_in[33];
    const float* ft_W1       = (const float*)d_in[34];
    const float* ft_b1       = (const float*)d_in[35];
    const float* ft_W2       = (const float*)d_in[36];
    const float* ft_b2       = (const float*)d_in[37];

    const int N = in_sizes[0];
    const int E = in_sizes[2] / 2;
    const int EPAD = ((E + 31 * N) / 32) * 32 + 32;   // padded-edge upper bound

    unsigned short* WB   = (unsigned short*)d_ws;                      // 24*WSLOT
    unsigned short* WB2  = WB + (size_t)24 * WSLOT;                    // 12*WSLOT2
    unsigned short* rbfs = WB2 + (size_t)12 * WSLOT2;                  // EPAD*16
    unsigned short* envs = rbfs + (size_t)EPAD * 16;                   // EPAD
    int*            js   = (int*)(envs + (size_t)EPAD);                // EPAD
    float* ws   = (float*)(js + (size_t)EPAD);
    float* S0   = ws;  ws += (size_t)N * 128;
    float* V    = ws;  ws += (size_t)N * 128;
    float* scS  = ws;  ws += (size_t)N * 140;
    float* bbA  = ws;  ws += (size_t)N * 3;
    float* bbT  = ws;  ws += (size_t)N * 3;
    float* scA  = ws;  ws += (size_t)N * 10;
    float* scT  = ws;  ws += (size_t)N * 10;
    __hip_bfloat16* PHI = (__hip_bfloat16*)ws;  ws += (size_t)N * 64;  // N*128 bf16
    int* peptr  = (int*)ws;  ws = (float*)((int*)ws + (N + 1));
    int* counts = (int*)ws;  ws = (float*)((int*)ws + N);
    int* cursor = (int*)ws;  ws = (float*)((int*)ws + N);

    (void)hipMemsetAsync(counts, 0, (size_t)2 * N * sizeof(int), stream);

    prep_weights_kernel<<<dim3(64, 12), 256, 0, stream>>>(
        msg_W1, msg_W2, dense_W1, dense_W2, WB);
    prep_sct_kernel<<<dim3(DIV_UP(WSLOT2, 256), 6), 256, 0, stream>>>(
        sct_W1, sct_W2, WB2);

    hist_kernel<<<DIV_UP(E, 256), 256, 0, stream>>>(nbr, counts, E);
    scan_kernel<<<1, 1024, 0, stream>>>(counts, peptr, N);
    geom_scatter_kernel<<<DIV_UP(E, 256), 256, 0, stream>>>(
        nbr, cg_xyz, peptr, cursor, rbfs, envs, js, E);

    concat_s_kernel<<<DIV_UP(N * 128, 256), 256, 0, stream>>>(S_in, res_embed, cg_z, S0, N);

    #define WHI(kind, conv) (WB + (size_t)(2 * ((kind) * 3 + (conv))) * WSLOT)
    #define WLO(kind, conv) (WB + (size_t)(2 * ((kind) * 3 + (conv)) + 1) * WSLOT)
    #define W2HI(kind, conv) (WB2 + (size_t)(2 * ((kind) * 3 + (conv))) * WSLOT2)
    #define W2LO(kind, conv) (WB2 + (size_t)(2 * ((kind) * 3 + (conv)) + 1) * WSLOT2)

    for (int i = 0; i < 3; ++i) {
        mlp2_mfma_kernel<48, false, false, __hip_bfloat16>
            <<<DIV_UP(N, 48), 256, 0, stream>>>(
            S0, WHI(0, i), WLO(0, i), msg_b1 + i * 128,
            WHI(1, i), WLO(1, i), msg_b2 + i * 128, PHI, N);
        gather_mfma_kernel<<<DIV_UP(N, 8), 256, 0, stream>>>(
            peptr, counts, rbfs, envs, js, (const unsigned short*)PHI,
            dist_W + (size_t)i * 16 * 128, dist_b + i * 128, V, N);
        mlp2_mfma_kernel<48, true, true, float>
            <<<DIV_UP(N, 48), 256, 0, stream>>>(
            V, WHI(2, i), WLO(2, i), dense_b1 + i * 128,
            WHI(3, i), WLO(3, i), dense_b2 + i * 128, S0, N);
    }

    head_kernel<3><<<DIV_UP(N, 4), 256, 0, stream>>>(
        S0, 128, 128, S0, 0, 0, bba_W1, bba_b1, bba_W2, bba_b2, bbA, 3, N);
    head_kernel<3><<<DIV_UP(N, 4), 256, 0, stream>>>(
        S0, 128, 128, bbA, 3, 3, bbt_W1, bbt_b1, bbt_W2, bbt_b2, bbT, 3, N);
    head_kernel<10><<<DIV_UP(N, 4), 256, 0, stream>>>(
        S0, 128, 128, S0, 0, 0, sca_W1, sca_b1, sca_W2, sca_b2, scA, 10, N);

    concat_sc_kernel<<<DIV_UP(N * 140, 256), 256, 0, stream>>>(S0, scA, scS, N);
    for (int i = 0; i < 3; ++i) {
        sct_mfma_kernel<<<DIV_UP(N, 32), 256, 0, stream>>>(
            scS, W2HI(0, i), W2LO(0, i), sct_b1 + i * 138,
            W2HI(1, i), W2LO(1, i), sct_b2 + i * 138, scS, N);
    }
    head_kernel<10><<<DIV_UP(N, 4), 256, 0, stream>>>(
        scS, 140, 138, scS, 0, 0, ft_W1, ft_b1, ft_W2, ft_b2, scT, 10, N);

    assemble_kernel<<<DIV_UP(N * 39, 256), 256, 0, stream>>>(
        cg_z, bb_dist_emb, sc_dist_emb, bbA, bbT, scA, scT, (float*)d_out, N);

    #undef WHI
    #undef WLO
    #undef W2HI
    #undef W2LO
}

// Round 11
// 754.110 us; speedup vs baseline: 1.3030x; 1.3030x over previous
//
#include <hip/hip_runtime.h>
#include <hip/hip_bf16.h>

#define DIV_UP(a,b) (((a)+(b)-1)/(b))

typedef __attribute__((ext_vector_type(8))) short bf16x8;
typedef __attribute__((ext_vector_type(4))) float f32x4;

__device__ __forceinline__ float silu_f(float x) {
    return x / (1.0f + __expf(-x));
}
__device__ __forceinline__ unsigned short f2bf(float x) {
    __hip_bfloat16 h = __float2bfloat16(x);
    return *reinterpret_cast<unsigned short*>(&h);
}
__device__ __forceinline__ float bf2f(unsigned short u) {
    unsigned int v = (unsigned int)u << 16;
    return __uint_as_float(v);
}
__device__ __forceinline__ void split_bf(float x, unsigned short& hi, unsigned short& lo) {
    hi = f2bf(x);
    lo = f2bf(x - bf2f(hi));
}
__device__ __forceinline__ bf16x8 pack8(unsigned int w0, unsigned int w1,
                                        unsigned int w2, unsigned int w3) {
    union { unsigned int u[4]; bf16x8 v; } t;
    t.u[0] = w0; t.u[1] = w1; t.u[2] = w2; t.u[3] = w3;
    return t.v;
}

#define WSLOT 16384   // 128*128 bf16 elements per weight slot (K=128 only)

// ---------------------------------------------------------------------------
// Weight prep (K=128 MLPs): f32 [128][128] -> bf16 hi/lo, transposed.
// ---------------------------------------------------------------------------
__global__ __launch_bounds__(256) void prep_weights_kernel(
    const float* __restrict__ msgW1, const float* __restrict__ msgW2,
    const float* __restrict__ denseW1, const float* __restrict__ denseW2,
    unsigned short* __restrict__ WB)
{
    int slot = blockIdx.y;
    int kind = slot / 3, conv = slot % 3;
    const float* base;
    switch (kind) {
        case 0: base = msgW1; break;
        case 1: base = msgW2; break;
        case 2: base = denseW1; break;
        default: base = denseW2; break;
    }
    const float* W = base + (size_t)conv * 128 * 128;
    int idx = blockIdx.x * 256 + threadIdx.x;
    if (idx >= 16384) return;
    int c = idx >> 7, k = idx & 127;
    float val = W[(size_t)k * 128 + c];
    unsigned short hi, lo;
    split_bf(val, hi, lo);
    WB[(size_t)(2 * slot) * WSLOT + idx]     = hi;
    WB[(size_t)(2 * slot + 1) * WSLOT + idx] = lo;
}

// ---------------------------------------------------------------------------
// CSR build: histogram -> single-block scan with PER-NODE PADDING to x32.
// ---------------------------------------------------------------------------
__global__ __launch_bounds__(256) void hist_kernel(
    const int* __restrict__ nbr, int* __restrict__ counts, int E)
{
    int e = blockIdx.x * 256 + threadIdx.x;
    if (e < E) atomicAdd(&counts[nbr[2 * e]], 1);
}

__global__ __launch_bounds__(1024) void scan_kernel(
    const int* __restrict__ counts, int* __restrict__ peptr, int N)
{
    __shared__ int part[1024];
    const int t = threadIdx.x;
    const int chunk = DIV_UP(N, 1024);
    int s = 0;
    for (int c = 0; c < chunk; ++c) {
        int idx = t * chunk + c;
        if (idx < N) s += (counts[idx] + 31) & ~31;
    }
    part[t] = s;
    __syncthreads();
    for (int off = 1; off < 1024; off <<= 1) {
        int v = (t >= off) ? part[t - off] : 0;
        __syncthreads();
        part[t] += v;
        __syncthreads();
    }
    int pre = (t > 0) ? part[t - 1] : 0;
    for (int c = 0; c < chunk; ++c) {
        int idx = t * chunk + c;
        if (idx < N) { peptr[idx] = pre; pre += (counts[idx] + 31) & ~31; }
    }
    if (t == 1023) peptr[N] = part[1023];
}

// ---------------------------------------------------------------------------
// Fused edge geometry + padded-CSR scatter.  Edge record: 16 contiguous bf16
// rbf values (env-premultiplied, 32 B), plus envs[p] (bf16) and js[p].
// Pad slots are NOT written; the gather kernel masks them via counts[n].
// ---------------------------------------------------------------------------
__global__ __launch_bounds__(256) void geom_scatter_kernel(
    const int* __restrict__ nbr, const float* __restrict__ xyz,
    const int* __restrict__ peptr, int* __restrict__ cursor,
    unsigned short* __restrict__ rbfs, unsigned short* __restrict__ envs,
    int* __restrict__ js, int E)
{
    int e = blockIdx.x * 256 + threadIdx.x;
    if (e >= E) return;
    int i = nbr[2 * e], j = nbr[2 * e + 1];
    float dx = xyz[3 * j + 0] - xyz[3 * i + 0];
    float dy = xyz[3 * j + 1] - xyz[3 * i + 1];
    float dz = xyz[3 * j + 2] - xyz[3 * i + 2];
    float dist = sqrtf(dx * dx + dy * dy + dz * dz);
    float x = dist * 0.3141592653589793f;   // pi/CUTOFF
    float s, c;
    __sincosf(x, &s, &c);
    float env = (dist < 10.0f) ? 0.5f * (c + 1.0f) : 0.0f;
    float inv_env = env / dist;
    float two_c = 2.0f * c;
    float sm1 = 0.0f, s0 = s;
    __align__(16) unsigned short ob[16];
    #pragma unroll
    for (int k = 0; k < 16; ++k) {
        ob[k] = f2bf(s0 * inv_env);
        float s1 = two_c * s0 - sm1;
        sm1 = s0; s0 = s1;
    }
    int p = peptr[i] + atomicAdd(&cursor[i], 1);
    uint4* rp = (uint4*)(rbfs + (size_t)p * 16);
    rp[0] = *(const uint4*)&ob[0];
    rp[1] = *(const uint4*)&ob[8];
    envs[p] = f2bf(env);
    js[p] = j;
}

// ---------------------------------------------------------------------------
// S0 = concat(S[N,124], res_embed[cg_z][N,4])  -> [N,128]
// ---------------------------------------------------------------------------
__global__ __launch_bounds__(256) void concat_s_kernel(
    const float* __restrict__ S, const float* __restrict__ res_embed,
    const int* __restrict__ z, float* __restrict__ S0, int N)
{
    int idx = blockIdx.x * 256 + threadIdx.x;
    if (idx >= N * 128) return;
    int n = idx >> 7, c = idx & 127;
    float val = (c < 124) ? S[n * 124 + c] : res_embed[z[n] * 4 + (c - 124)];
    S0[idx] = val;
}

// ---------------------------------------------------------------------------
// scS = concat(S0[N,128], scA[N,10]) -> [N,140] (2 pad zeros)
// ---------------------------------------------------------------------------
__global__ __launch_bounds__(256) void concat_sc_kernel(
    const float* __restrict__ S0, const float* __restrict__ scA,
    float* __restrict__ scS, int N)
{
    int idx = blockIdx.x * 256 + threadIdx.x;
    if (idx >= N * 140) return;
    int n = idx / 140, c = idx - n * 140;
    float val = 0.0f;
    if (c < 128)       val = S0[n * 128 + c];
    else if (c < 138)  val = scA[n * 10 + (c - 128)];
    scS[idx] = val;
}

// ---------------------------------------------------------------------------
// Split-bf16 MFMA two-stage MLP, K=128, LDS 56 KB (r6-proven).
// ---------------------------------------------------------------------------
template<int MT, bool PREACT, bool RESID, typename OutT>
__global__ __launch_bounds__(256) void mlp2_mfma_kernel(
    const float* __restrict__ X,
    const unsigned short* __restrict__ W1hi, const unsigned short* __restrict__ W1lo,
    const float* __restrict__ b1,
    const unsigned short* __restrict__ W2hi, const unsigned short* __restrict__ W2lo,
    const float* __restrict__ b2,
    OutT* __restrict__ Y, int nrows)
{
    constexpr int RB   = MT / 16;
    constexpr int ROWB = 256;
    __shared__ __align__(16) unsigned short XHhi[MT * 128];
    __shared__ __align__(16) unsigned short XHlo[MT * 128];
    __shared__ __align__(16) unsigned short WS[128 * 128];

    const int tid  = threadIdx.x;
    const int wave = tid >> 6;
    const int lane = tid & 63;
    const int l15  = lane & 15;
    const int kg   = lane >> 4;
    const int row0 = blockIdx.x * MT;

    for (int idx = tid; idx < MT * 32; idx += 256) {
        int r = idx >> 5, q = idx & 31;
        int gr = row0 + r;
        float4 xv = make_float4(0.f, 0.f, 0.f, 0.f);
        if (gr < nrows) xv = *(const float4*)(X + (size_t)gr * 128 + 4 * q);
        if (PREACT) { xv.x = silu_f(xv.x); xv.y = silu_f(xv.y);
                      xv.z = silu_f(xv.z); xv.w = silu_f(xv.w); }
        ushort4 h, l;
        split_bf(xv.x, h.x, l.x); split_bf(xv.y, h.y, l.y);
        split_bf(xv.z, h.z, l.z); split_bf(xv.w, h.w, l.w);
        int off = (8 * q) ^ ((r & 7) << 4);
        *(ushort4*)((char*)XHhi + r * ROWB + off) = h;
        *(ushort4*)((char*)XHlo + r * ROWB + off) = l;
    }

    f32x4 acc[RB][2];

    #define STAGE_W(WPTR)                                                       \
        for (int idx = tid; idx < 2048; idx += 256) {                           \
            int r = idx >> 4;                                                   \
            int byt = (idx & 15) * 16;                                          \
            *(uint4*)((char*)WS + r * ROWB + (byt ^ ((r & 7) << 4))) =          \
                *(const uint4*)((WPTR) + (size_t)idx * 8);                      \
        }

    #define PASS(WITH_LO)                                                       \
        _Pragma("unroll")                                                       \
        for (int kk = 0; kk < 4; ++kk) {                                        \
            const int kbyte = kk * 64 + kg * 16;                                \
            bf16x8 ah[RB], al[RB];                                              \
            _Pragma("unroll")                                                   \
            for (int rb = 0; rb < RB; ++rb) {                                   \
                int r = 16 * rb + l15;                                          \
                int off = kbyte ^ ((r & 7) << 4);                               \
                ah[rb] = *(const bf16x8*)((const char*)XHhi + r * ROWB + off);  \
                if (WITH_LO)                                                    \
                    al[rb] = *(const bf16x8*)((const char*)XHlo + r * ROWB + off); \
            }                                                                   \
            _Pragma("unroll")                                                   \
            for (int cbi = 0; cbi < 2; ++cbi) {                                 \
                int rw = 16 * (wave + 4 * cbi) + l15;                           \
                int offw = kbyte ^ ((rw & 7) << 4);                             \
                bf16x8 bw = *(const bf16x8*)((const char*)WS + rw * ROWB + offw); \
                _Pragma("unroll")                                               \
                for (int rb = 0; rb < RB; ++rb) {                               \
                    f32x4 t = acc[rb][cbi];                                     \
                    t = __builtin_amdgcn_mfma_f32_16x16x32_bf16(ah[rb], bw, t, 0, 0, 0); \
                    if (WITH_LO)                                                \
                        t = __builtin_amdgcn_mfma_f32_16x16x32_bf16(al[rb], bw, t, 0, 0, 0); \
                    acc[rb][cbi] = t;                                           \
                }                                                               \
            }                                                                   \
        }

    #pragma unroll
    for (int a = 0; a < RB; ++a) { acc[a][0] = (f32x4){0,0,0,0}; acc[a][1] = (f32x4){0,0,0,0}; }
    STAGE_W(W1hi)
    __syncthreads();
    PASS(true)
    __syncthreads();
    STAGE_W(W1lo)
    __syncthreads();
    PASS(false)
    __syncthreads();

    #pragma unroll
    for (int cbi = 0; cbi < 2; ++cbi) {
        int col = 16 * (wave + 4 * cbi) + l15;
        float b1v = b1[col];
        #pragma unroll
        for (int rb = 0; rb < RB; ++rb)
            #pragma unroll
            for (int i = 0; i < 4; ++i) {
                int r = 16 * rb + kg * 4 + i;
                float h = silu_f(acc[rb][cbi][i] + b1v);
                unsigned short hh, hl;
                split_bf(h, hh, hl);
                int off = (2 * col) ^ ((r & 7) << 4);
                *(unsigned short*)((char*)XHhi + r * ROWB + off) = hh;
                *(unsigned short*)((char*)XHlo + r * ROWB + off) = hl;
            }
    }
    #pragma unroll
    for (int a = 0; a < RB; ++a) { acc[a][0] = (f32x4){0,0,0,0}; acc[a][1] = (f32x4){0,0,0,0}; }
    STAGE_W(W2hi)
    __syncthreads();
    PASS(true)
    __syncthreads();
    STAGE_W(W2lo)
    __syncthreads();
    PASS(false)
    #undef PASS
    #undef STAGE_W

    #pragma unroll
    for (int cbi = 0; cbi < 2; ++cbi) {
        int col = 16 * (wave + 4 * cbi) + l15;
        float b2v = b2[col];
        #pragma unroll
        for (int rb = 0; rb < RB; ++rb)
            #pragma unroll
            for (int i = 0; i < 4; ++i) {
                int gr = row0 + 16 * rb + kg * 4 + i;
                if (gr < nrows) {
                    size_t off = (size_t)gr * 128 + col;
                    float val = acc[rb][cbi][i] + b2v;
                    if (RESID) val += (float)Y[off];
                    if constexpr (sizeof(OutT) == 2)
                        Y[off] = __float2bfloat16(val);
                    else
                        Y[off] = val;
                }
            }
    }
}

// ---------------------------------------------------------------------------
// Generic two-stage fp32 MLP (r3-proven), for the K=138 sct layers.
// ---------------------------------------------------------------------------
template<int K, bool PREACT, bool RESID, typename OutT>
__global__ __launch_bounds__(256) void mlp2_kernel(
    const float* __restrict__ X, int ldX,
    const float* __restrict__ W1, const float* __restrict__ b1,
    const float* __restrict__ W2, const float* __restrict__ b2,
    OutT* __restrict__ Y, int ldY, int nrows)
{
    constexpr int NC = (K + 31) / 32;
    constexpr int ROWS = 48;
    constexpr int RR = 6;
    __shared__ float Xs[ROWS * K];
    __shared__ float Hs[ROWS * K];
    const int tid = threadIdx.x;
    const int row0 = blockIdx.x * ROWS;

    for (int idx = tid; idx < ROWS * K; idx += 256) {
        int r = idx / K, c = idx - r * K;
        int gr = row0 + r;
        float x = (gr < nrows) ? X[(size_t)gr * ldX + c] : 0.0f;
        if (PREACT) x = silu_f(x);
        Xs[idx] = x;
    }
    __syncthreads();

    const int cc = tid & 31;
    const int r0 = (tid >> 5) * RR;

    float acc[NC][RR];
    #pragma unroll
    for (int jc = 0; jc < NC; ++jc) {
        int col = cc + 32 * jc;
        float bv = (col < K) ? b1[col] : 0.0f;
        #pragma unroll
        for (int rr = 0; rr < RR; ++rr) acc[jc][rr] = bv;
    }
    for (int k = 0; k < K; ++k) {
        float w[NC];
        #pragma unroll
        for (int jc = 0; jc < NC; ++jc) {
            int col = cc + 32 * jc;
            w[jc] = (col < K) ? W1[k * K + col] : 0.0f;
        }
        float xv[RR];
        #pragma unroll
        for (int rr = 0; rr < RR; ++rr) xv[rr] = Xs[(r0 + rr) * K + k];
        #pragma unroll
        for (int jc = 0; jc < NC; ++jc)
            #pragma unroll
            for (int rr = 0; rr < RR; ++rr)
                acc[jc][rr] = fmaf(xv[rr], w[jc], acc[jc][rr]);
    }
    #pragma unroll
    for (int jc = 0; jc < NC; ++jc) {
        int col = cc + 32 * jc;
        if (col < K) {
            #pragma unroll
            for (int rr = 0; rr < RR; ++rr)
                Hs[(r0 + rr) * K + col] = silu_f(acc[jc][rr]);
        }
    }
    __syncthreads();

    #pragma unroll
    for (int jc = 0; jc < NC; ++jc) {
        int col = cc + 32 * jc;
        float bv = (col < K) ? b2[col] : 0.0f;
        #pragma unroll
        for (int rr = 0; rr < RR; ++rr) acc[jc][rr] = bv;
    }
    for (int k = 0; k < K; ++k) {
        float w[NC];
        #pragma unroll
        for (int jc = 0; jc < NC; ++jc) {
            int col = cc + 32 * jc;
            w[jc] = (col < K) ? W2[k * K + col] : 0.0f;
        }
        float xv[RR];
        #pragma unroll
        for (int rr = 0; rr < RR; ++rr) xv[rr] = Hs[(r0 + rr) * K + k];
        #pragma unroll
        for (int jc = 0; jc < NC; ++jc)
            #pragma unroll
            for (int rr = 0; rr < RR; ++rr)
                acc[jc][rr] = fmaf(xv[rr], w[jc], acc[jc][rr]);
    }
    #pragma unroll
    for (int jc = 0; jc < NC; ++jc) {
        int col = cc + 32 * jc;
        if (col < K) {
            #pragma unroll
            for (int rr = 0; rr < RR; ++rr) {
                int gr = row0 + r0 + rr;
                if (gr < nrows) {
                    size_t off = (size_t)gr * ldY + col;
                    float val = acc[jc][rr];
                    if (RESID) val += (float)Y[off];
                    if constexpr (sizeof(OutT) == 2)
                        Y[off] = __float2bfloat16(val);
                    else
                        Y[off] = val;
                }
            }
        }
    }
}

// ---------------------------------------------------------------------------
// Register-direct MFMA gather, COLUMN-SPLIT: 2 waves per node, each owning
// 4 of the 8 column-blocks (64 phi columns).  Chunk-loop math is r8-proven;
// env handled via per-chunk zero-C MFMA + scalar accumulate (r10-proven).
//   T = rbf^T(16x32) @ Phi(32x128) per node;
//   v[n][c] = sum_k dW[k][c]*T[k][c] + db[c]*T_env[c]
// ---------------------------------------------------------------------------
__global__ __launch_bounds__(256) void gather_mfma_kernel(
    const int* __restrict__ peptr, const int* __restrict__ counts,
    const unsigned short* __restrict__ rbfs,   // [EPAD][16] bf16
    const unsigned short* __restrict__ envs,   // [EPAD] bf16
    const int* __restrict__ js,                // [EPAD]
    const unsigned short* __restrict__ phi,    // [N][128] bf16
    const float* __restrict__ distW, const float* __restrict__ distb,
    float* __restrict__ v, int N)
{
    const int wv = blockIdx.x * 4 + (threadIdx.x >> 6);
    const int lane = threadIdx.x & 63;
    const int n = wv >> 1;
    const int h = wv & 1;               // column half: cols 64h .. 64h+63
    if (n >= N) return;
    const int l15 = lane & 15;
    const int lg  = lane >> 4;

    f32x4 acc[4];
    float eac[4];
    #pragma unroll
    for (int cb = 0; cb < 4; ++cb) { acc[cb] = (f32x4){0,0,0,0}; eac[cb] = 0.f; }

    const int p0 = peptr[n], p1 = peptr[n + 1];
    const int deg = counts[n];

    for (int p = p0; p < p1; p += 32) {
        const int rem = deg - ((p - p0) + 8 * lg);   // slots i < rem are real edges

        // ---- row indices (masked to row 0 for pads; A=0 kills them) ----
        const int* jb = js + p + 8 * lg;
        int jr[8];
        #pragma unroll
        for (int i = 0; i < 8; ++i)
            jr[i] = (i < rem) ? jb[i] : 0;

        // ---- A-frag: rbf[slot][l15], masked ----
        const unsigned short* ab = rbfs + (size_t)(p + 8 * lg) * 16 + l15;
        unsigned int aw[4];
        #pragma unroll
        for (int w = 0; w < 4; ++w) {
            unsigned int lo = (2 * w     < rem) ? (unsigned int)ab[(2 * w) * 16]     : 0u;
            unsigned int hi = (2 * w + 1 < rem) ? (unsigned int)ab[(2 * w + 1) * 16] : 0u;
            aw[w] = lo | (hi << 16);
        }
        bf16x8 af = pack8(aw[0], aw[1], aw[2], aw[3]);

        // ---- env frag (A2: env in row 0) ----
        unsigned int ew[4] = {0u, 0u, 0u, 0u};
        if (l15 == 0) {
            const unsigned short* eb = envs + p + 8 * lg;
            #pragma unroll
            for (int w = 0; w < 4; ++w) {
                unsigned int lo = (2 * w     < rem) ? (unsigned int)eb[2 * w]     : 0u;
                unsigned int hi = (2 * w + 1 < rem) ? (unsigned int)eb[2 * w + 1] : 0u;
                ew[w] = lo | (hi << 16);
            }
        }
        bf16x8 a2f = pack8(ew[0], ew[1], ew[2], ew[3]);

        // ---- B-frags: phi[jr[i]][64h + cbi*16 + l15] ----
        const unsigned short* pb0 = phi + (size_t)jr[0] * 128 + 64 * h + l15;
        const unsigned short* pb1 = phi + (size_t)jr[1] * 128 + 64 * h + l15;
        const unsigned short* pb2 = phi + (size_t)jr[2] * 128 + 64 * h + l15;
        const unsigned short* pb3 = phi + (size_t)jr[3] * 128 + 64 * h + l15;
        const unsigned short* pb4 = phi + (size_t)jr[4] * 128 + 64 * h + l15;
        const unsigned short* pb5 = phi + (size_t)jr[5] * 128 + 64 * h + l15;
        const unsigned short* pb6 = phi + (size_t)jr[6] * 128 + 64 * h + l15;
        const unsigned short* pb7 = phi + (size_t)jr[7] * 128 + 64 * h + l15;

        #pragma unroll
        for (int cbi = 0; cbi < 4; ++cbi) {
            const int o = cbi * 16;
            unsigned int b0 = (unsigned int)pb0[o] | ((unsigned int)pb1[o] << 16);
            unsigned int b1 = (unsigned int)pb2[o] | ((unsigned int)pb3[o] << 16);
            unsigned int b2 = (unsigned int)pb4[o] | ((unsigned int)pb5[o] << 16);
            unsigned int b3 = (unsigned int)pb6[o] | ((unsigned int)pb7[o] << 16);
            bf16x8 bf = pack8(b0, b1, b2, b3);
            acc[cbi] = __builtin_amdgcn_mfma_f32_16x16x32_bf16(af, bf, acc[cbi], 0, 0, 0);
            f32x4 z = (f32x4){0, 0, 0, 0};
            z = __builtin_amdgcn_mfma_f32_16x16x32_bf16(a2f, bf, z, 0, 0, 0);
            eac[cbi] += z[0];
        }
    }

    // ---- epilogue: dot with dW rows, add db*T_env, reduce across lane-groups
    #pragma unroll
    for (int cbi = 0; cbi < 4; ++cbi) {
        int col = 64 * h + cbi * 16 + l15;
        float part = acc[cbi][0] * distW[(lg * 4 + 0) * 128 + col];
        part = fmaf(acc[cbi][1], distW[(lg * 4 + 1) * 128 + col], part);
        part = fmaf(acc[cbi][2], distW[(lg * 4 + 2) * 128 + col], part);
        part = fmaf(acc[cbi][3], distW[(lg * 4 + 3) * 128 + col], part);
        if (lg == 0) part = fmaf(eac[cbi], distb[col], part);
        part += __shfl_xor(part, 16, 64);
        part += __shfl_xor(part, 32, 64);
        if (lane < 16) v[(size_t)n * 128 + col] = part;
    }
}

// ---------------------------------------------------------------------------
// Small head: out = silu( silu(x) @ W1 + b1 ) @ W2 + b2   (final linear)
// ---------------------------------------------------------------------------
template<int M>
__global__ __launch_bounds__(256) void head_kernel(
    const float* __restrict__ X, int ldX, int K1,
    const float* __restrict__ X2, int ldX2, int K2,
    const float* __restrict__ W1, const float* __restrict__ b1,
    const float* __restrict__ W2, const float* __restrict__ b2,
    float* __restrict__ out, int ldOut, int nrows)
{
    const int wid = threadIdx.x >> 6;
    const int lane = threadIdx.x & 63;
    const int n = blockIdx.x * 4 + wid;
    if (n >= nrows) return;
    const int K = K1 + K2;
    float sx[3];
    #pragma unroll
    for (int t = 0; t < 3; ++t) {
        int k = lane + 64 * t;
        float v = 0.0f;
        if (k < K1) v = X[(size_t)n * ldX + k];
        else if (k < K) v = X2[(size_t)n * ldX2 + (k - K1)];
        sx[t] = (k < K) ? silu_f(v) : 0.0f;
    }
    float acc[M];
    #pragma unroll
    for (int m = 0; m < M; ++m) {
        float a = 0.0f;
        #pragma unroll
        for (int t = 0; t < 3; ++t) {
            int k = lane + 64 * t;
            if (k < K) a = fmaf(sx[t], W1[k * M + m], a);
        }
        acc[m] = a;
    }
    #pragma unroll
    for (int m = 0; m < M; ++m) {
        #pragma unroll
        for (int off = 32; off > 0; off >>= 1)
            acc[m] += __shfl_xor(acc[m], off, 64);
    }
    float tm[M];
    #pragma unroll
    for (int m = 0; m < M; ++m) tm[m] = silu_f(acc[m] + b1[m]);
    if (lane < M) {
        float o = b2[lane];
        #pragma unroll
        for (int m = 0; m < M; ++m) o = fmaf(tm[m], W2[m * M + lane], o);
        out[(size_t)n * ldOut + lane] = o;
    }
}

// ---------------------------------------------------------------------------
// Output assembly: out[N][13][3]
// ---------------------------------------------------------------------------
__global__ __launch_bounds__(256) void assemble_kernel(
    const int* __restrict__ z,
    const float* __restrict__ bbde, const float* __restrict__ scde,
    const float* __restrict__ bbA, const float* __restrict__ bbT,
    const float* __restrict__ scA, const float* __restrict__ scT,
    float* __restrict__ out, int N)
{
    int idx = blockIdx.x * 256 + threadIdx.x;
    if (idx >= N * 39) return;
    int n = idx / 39;
    int s = idx - n * 39;
    int row = s / 3;
    int col = s - row * 3;
    float val;
    if (row < 3) {
        if (col == 0)      val = bbde[z[n] * 3 + row];
        else if (col == 1) val = bbA[n * 3 + row];
        else               val = bbT[n * 3 + row];
    } else {
        int r = row - 3;
        if (col == 0)      val = scde[z[n] * 10 + r];
        else if (col == 1) val = scA[n * 10 + r];
        else               val = scT[n * 10 + r];
    }
    out[idx] = val;
}

extern "C" void kernel_launch(void* const* d_in, const int* in_sizes, int n_in,
                              void* d_out, int out_size, void* d_ws, size_t ws_size,
                              hipStream_t stream)
{
    const int*   cg_z        = (const int*)d_in[0];
    const float* cg_xyz      = (const float*)d_in[1];
    const int*   nbr         = (const int*)d_in[2];
    // d_in[3] = mapping (unused by reference)
    const float* S_in        = (const float*)d_in[4];
    const float* res_embed   = (const float*)d_in[5];
    const float* msg_W1      = (const float*)d_in[6];
    const float* msg_b1      = (const float*)d_in[7];
    const float* msg_W2      = (const float*)d_in[8];
    const float* msg_b2      = (const float*)d_in[9];
    const float* dist_W      = (const float*)d_in[10];
    const float* dist_b      = (const float*)d_in[11];
    const float* dense_W1    = (const float*)d_in[12];
    const float* dense_b1    = (const float*)d_in[13];
    const float* dense_W2    = (const float*)d_in[14];
    const float* dense_b2    = (const float*)d_in[15];
    const float* bb_dist_emb = (const float*)d_in[16];
    const float* sc_dist_emb = (const float*)d_in[17];
    const float* bba_W1      = (const float*)d_in[18];
    const float* bba_b1      = (const float*)d_in[19];
    const float* bba_W2      = (const float*)d_in[20];
    const float* bba_b2      = (const float*)d_in[21];
    const float* sca_W1      = (const float*)d_in[22];
    const float* sca_b1      = (const float*)d_in[23];
    const float* sca_W2      = (const float*)d_in[24];
    const float* sca_b2      = (const float*)d_in[25];
    const float* bbt_W1      = (const float*)d_in[26];
    const float* bbt_b1      = (const float*)d_in[27];
    const float* bbt_W2      = (const float*)d_in[28];
    const float* bbt_b2      = (const float*)d_in[29];
    const float* sct_W1      = (const float*)d_in[30];
    const float* sct_b1      = (const float*)d_in[31];
    const float* sct_W2      = (const float*)d_in[32];
    const float* sct_b2      = (const float*)d_in[33];
    const float* ft_W1       = (const float*)d_in[34];
    const float* ft_b1       = (const float*)d_in[35];
    const float* ft_W2       = (const float*)d_in[36];
    const float* ft_b2       = (const float*)d_in[37];

    const int N = in_sizes[0];
    const int E = in_sizes[2] / 2;
    const int EPAD = ((E + 31 * N) / 32) * 32 + 32;   // padded-edge upper bound

    unsigned short* WB   = (unsigned short*)d_ws;                      // 24*WSLOT
    unsigned short* rbfs = WB + (size_t)24 * WSLOT;                    // EPAD*16
    unsigned short* envs = rbfs + (size_t)EPAD * 16;                   // EPAD
    int*            js   = (int*)(envs + (size_t)EPAD);                // EPAD
    float* ws   = (float*)(js + (size_t)EPAD);
    float* S0   = ws;  ws += (size_t)N * 128;
    float* V    = ws;  ws += (size_t)N * 128;
    float* scS  = ws;  ws += (size_t)N * 140;
    float* bbA  = ws;  ws += (size_t)N * 3;
    float* bbT  = ws;  ws += (size_t)N * 3;
    float* scA  = ws;  ws += (size_t)N * 10;
    float* scT  = ws;  ws += (size_t)N * 10;
    __hip_bfloat16* PHI = (__hip_bfloat16*)ws;  ws += (size_t)N * 64;  // N*128 bf16
    int* peptr  = (int*)ws;  ws = (float*)((int*)ws + (N + 1));
    int* counts = (int*)ws;  ws = (float*)((int*)ws + N);
    int* cursor = (int*)ws;  ws = (float*)((int*)ws + N);

    // Only counts+cursor need zeroing (pads are masked in-kernel via counts)
    (void)hipMemsetAsync(counts, 0, (size_t)2 * N * sizeof(int), stream);

    prep_weights_kernel<<<dim3(64, 12), 256, 0, stream>>>(
        msg_W1, msg_W2, dense_W1, dense_W2, WB);

    hist_kernel<<<DIV_UP(E, 256), 256, 0, stream>>>(nbr, counts, E);
    scan_kernel<<<1, 1024, 0, stream>>>(counts, peptr, N);
    geom_scatter_kernel<<<DIV_UP(E, 256), 256, 0, stream>>>(
        nbr, cg_xyz, peptr, cursor, rbfs, envs, js, E);

    concat_s_kernel<<<DIV_UP(N * 128, 256), 256, 0, stream>>>(S_in, res_embed, cg_z, S0, N);

    #define WHI(kind, conv) (WB + (size_t)(2 * ((kind) * 3 + (conv))) * WSLOT)
    #define WLO(kind, conv) (WB + (size_t)(2 * ((kind) * 3 + (conv)) + 1) * WSLOT)

    for (int i = 0; i < 3; ++i) {
        mlp2_mfma_kernel<48, false, false, __hip_bfloat16>
            <<<DIV_UP(N, 48), 256, 0, stream>>>(
            S0, WHI(0, i), WLO(0, i), msg_b1 + i * 128,
            WHI(1, i), WLO(1, i), msg_b2 + i * 128, PHI, N);
        gather_mfma_kernel<<<DIV_UP(2 * N, 4), 256, 0, stream>>>(
            peptr, counts, rbfs, envs, js, (const unsigned short*)PHI,
            dist_W + (size_t)i * 16 * 128, dist_b + i * 128, V, N);
        mlp2_mfma_kernel<48, true, true, float>
            <<<DIV_UP(N, 48), 256, 0, stream>>>(
            V, WHI(2, i), WLO(2, i), dense_b1 + i * 128,
            WHI(3, i), WLO(3, i), dense_b2 + i * 128, S0, N);
    }

    head_kernel<3><<<DIV_UP(N, 4), 256, 0, stream>>>(
        S0, 128, 128, S0, 0, 0, bba_W1, bba_b1, bba_W2, bba_b2, bbA, 3, N);
    head_kernel<3><<<DIV_UP(N, 4), 256, 0, stream>>>(
        S0, 128, 128, bbA, 3, 3, bbt_W1, bbt_b1, bbt_W2, bbt_b2, bbT, 3, N);
    head_kernel<10><<<DIV_UP(N, 4), 256, 0, stream>>>(
        S0, 128, 128, S0, 0, 0, sca_W1, sca_b1, sca_W2, sca_b2, scA, 10, N);

    concat_sc_kernel<<<DIV_UP(N * 140, 256), 256, 0, stream>>>(S0, scA, scS, N);
    for (int i = 0; i < 3; ++i) {
        mlp2_kernel<138, true, true, float><<<DIV_UP(N, 48), 256, 0, stream>>>(
            scS, 140, sct_W1 + (size_t)i * 138 * 138, sct_b1 + i * 138,
            sct_W2 + (size_t)i * 138 * 138, sct_b2 + i * 138, scS, 140, N);
    }
    head_kernel<10><<<DIV_UP(N, 4), 256, 0, stream>>>(
        scS, 140, 138, scS, 0, 0, ft_W1, ft_b1, ft_W2, ft_b2, scT, 10, N);

    assemble_kernel<<<DIV_UP(N * 39, 256), 256, 0, stream>>>(
        cg_z, bb_dist_emb, sc_dist_emb, bbA, bbT, scA, scT, (float*)d_out, N);

    #undef WHI
    #undef WLO
}

// Round 12
// 653.514 us; speedup vs baseline: 1.5035x; 1.1539x over previous
//
#include <hip/hip_runtime.h>
#include <hip/hip_bf16.h>

#define DIV_UP(a,b) (((a)+(b)-1)/(b))

typedef __attribute__((ext_vector_type(8))) short bf16x8;
typedef __attribute__((ext_vector_type(4))) float f32x4;

__device__ __forceinline__ float silu_f(float x) {
    return x / (1.0f + __expf(-x));
}
__device__ __forceinline__ unsigned short f2bf(float x) {
    __hip_bfloat16 h = __float2bfloat16(x);
    return *reinterpret_cast<unsigned short*>(&h);
}
__device__ __forceinline__ float bf2f(unsigned short u) {
    unsigned int v = (unsigned int)u << 16;
    return __uint_as_float(v);
}
__device__ __forceinline__ void split_bf(float x, unsigned short& hi, unsigned short& lo) {
    hi = f2bf(x);
    lo = f2bf(x - bf2f(hi));
}
__device__ __forceinline__ bf16x8 pack8(unsigned int w0, unsigned int w1,
                                        unsigned int w2, unsigned int w3) {
    union { unsigned int u[4]; bf16x8 v; } t;
    t.u[0] = w0; t.u[1] = w1; t.u[2] = w2; t.u[3] = w3;
    return t.v;
}

#define WSLOT 16384   // 128*128 bf16 elements per weight slot (K=128 only)

// ---------------------------------------------------------------------------
// Weight prep (K=128 MLPs): f32 [128][128] -> bf16 hi/lo, transposed.
// ---------------------------------------------------------------------------
__global__ __launch_bounds__(256) void prep_weights_kernel(
    const float* __restrict__ msgW1, const float* __restrict__ msgW2,
    const float* __restrict__ denseW1, const float* __restrict__ denseW2,
    unsigned short* __restrict__ WB)
{
    int slot = blockIdx.y;
    int kind = slot / 3, conv = slot % 3;
    const float* base;
    switch (kind) {
        case 0: base = msgW1; break;
        case 1: base = msgW2; break;
        case 2: base = denseW1; break;
        default: base = denseW2; break;
    }
    const float* W = base + (size_t)conv * 128 * 128;
    int idx = blockIdx.x * 256 + threadIdx.x;
    if (idx >= 16384) return;
    int c = idx >> 7, k = idx & 127;
    float val = W[(size_t)k * 128 + c];
    unsigned short hi, lo;
    split_bf(val, hi, lo);
    WB[(size_t)(2 * slot) * WSLOT + idx]     = hi;
    WB[(size_t)(2 * slot + 1) * WSLOT + idx] = lo;
}

// ---------------------------------------------------------------------------
// CSR build: histogram -> single-block scan with PER-NODE PADDING to x32.
// ---------------------------------------------------------------------------
__global__ __launch_bounds__(256) void hist_kernel(
    const int* __restrict__ nbr, int* __restrict__ counts, int E)
{
    int e = blockIdx.x * 256 + threadIdx.x;
    if (e < E) atomicAdd(&counts[nbr[2 * e]], 1);
}

__global__ __launch_bounds__(1024) void scan_kernel(
    const int* __restrict__ counts, int* __restrict__ peptr, int N)
{
    __shared__ int part[1024];
    const int t = threadIdx.x;
    const int chunk = DIV_UP(N, 1024);
    int s = 0;
    for (int c = 0; c < chunk; ++c) {
        int idx = t * chunk + c;
        if (idx < N) s += (counts[idx] + 31) & ~31;
    }
    part[t] = s;
    __syncthreads();
    for (int off = 1; off < 1024; off <<= 1) {
        int v = (t >= off) ? part[t - off] : 0;
        __syncthreads();
        part[t] += v;
        __syncthreads();
    }
    int pre = (t > 0) ? part[t - 1] : 0;
    for (int c = 0; c < chunk; ++c) {
        int idx = t * chunk + c;
        if (idx < N) { peptr[idx] = pre; pre += (counts[idx] + 31) & ~31; }
    }
    if (t == 1023) peptr[N] = part[1023];
}

// ---------------------------------------------------------------------------
// Fused edge geometry + padded-CSR scatter, writing rbf (env-premultiplied,
// bf16) DIRECTLY IN MFMA A-FRAGMENT ORDER (r7-proven layout):
//   chunk tile = 512 u16; element A[r][kk] at flat r*8 + (kk>>3)*128 + (kk&7)
//   (A lane l holds A[l&15][8*(l>>4)+i] at flat lane*8+i)
// envs (bf16) and js at padded positions; pad slots pre-zeroed by memset.
// ---------------------------------------------------------------------------
__global__ __launch_bounds__(256) void geom_scatter_kernel(
    const int* __restrict__ nbr, const float* __restrict__ xyz,
    const int* __restrict__ peptr, int* __restrict__ cursor,
    unsigned short* __restrict__ rbfT, unsigned short* __restrict__ envs,
    int* __restrict__ js, int E)
{
    int e = blockIdx.x * 256 + threadIdx.x;
    if (e >= E) return;
    int i = nbr[2 * e], j = nbr[2 * e + 1];
    float dx = xyz[3 * j + 0] - xyz[3 * i + 0];
    float dy = xyz[3 * j + 1] - xyz[3 * i + 1];
    float dz = xyz[3 * j + 2] - xyz[3 * i + 2];
    float dist = sqrtf(dx * dx + dy * dy + dz * dz);
    float x = dist * 0.3141592653589793f;   // pi/CUTOFF
    float s, c;
    __sincosf(x, &s, &c);
    float env = (dist < 10.0f) ? 0.5f * (c + 1.0f) : 0.0f;
    float inv_env = env / dist;
    float two_c = 2.0f * c;
    float sm1 = 0.0f, s0 = s;
    unsigned short ob[16];
    #pragma unroll
    for (int k = 0; k < 16; ++k) {
        ob[k] = f2bf(s0 * inv_env);
        float s1 = two_c * s0 - sm1;
        sm1 = s0; s0 = s1;
    }
    int p = peptr[i] + atomicAdd(&cursor[i], 1);
    unsigned short* tb = rbfT + (size_t)(p >> 5) * 512;
    const int kk = p & 31;
    const int koff = ((kk >> 3) << 7) | (kk & 7);
    #pragma unroll
    for (int r = 0; r < 16; ++r)
        tb[koff + r * 8] = ob[r];
    envs[p] = f2bf(env);
    js[p] = j;
}

// ---------------------------------------------------------------------------
// S0 = concat(S[N,124], res_embed[cg_z][N,4])  -> [N,128]
// ---------------------------------------------------------------------------
__global__ __launch_bounds__(256) void concat_s_kernel(
    const float* __restrict__ S, const float* __restrict__ res_embed,
    const int* __restrict__ z, float* __restrict__ S0, int N)
{
    int idx = blockIdx.x * 256 + threadIdx.x;
    if (idx >= N * 128) return;
    int n = idx >> 7, c = idx & 127;
    float val = (c < 124) ? S[n * 124 + c] : res_embed[z[n] * 4 + (c - 124)];
    S0[idx] = val;
}

// ---------------------------------------------------------------------------
// Split-bf16 MFMA two-stage MLP, K=128, LDS 56 KB (r6-proven).
// ---------------------------------------------------------------------------
template<int MT, bool PREACT, bool RESID, typename OutT>
__global__ __launch_bounds__(256) void mlp2_mfma_kernel(
    const float* __restrict__ X,
    const unsigned short* __restrict__ W1hi, const unsigned short* __restrict__ W1lo,
    const float* __restrict__ b1,
    const unsigned short* __restrict__ W2hi, const unsigned short* __restrict__ W2lo,
    const float* __restrict__ b2,
    OutT* __restrict__ Y, int nrows)
{
    constexpr int RB   = MT / 16;
    constexpr int ROWB = 256;
    __shared__ __align__(16) unsigned short XHhi[MT * 128];
    __shared__ __align__(16) unsigned short XHlo[MT * 128];
    __shared__ __align__(16) unsigned short WS[128 * 128];

    const int tid  = threadIdx.x;
    const int wave = tid >> 6;
    const int lane = tid & 63;
    const int l15  = lane & 15;
    const int kg   = lane >> 4;
    const int row0 = blockIdx.x * MT;

    for (int idx = tid; idx < MT * 32; idx += 256) {
        int r = idx >> 5, q = idx & 31;
        int gr = row0 + r;
        float4 xv = make_float4(0.f, 0.f, 0.f, 0.f);
        if (gr < nrows) xv = *(const float4*)(X + (size_t)gr * 128 + 4 * q);
        if (PREACT) { xv.x = silu_f(xv.x); xv.y = silu_f(xv.y);
                      xv.z = silu_f(xv.z); xv.w = silu_f(xv.w); }
        ushort4 h, l;
        split_bf(xv.x, h.x, l.x); split_bf(xv.y, h.y, l.y);
        split_bf(xv.z, h.z, l.z); split_bf(xv.w, h.w, l.w);
        int off = (8 * q) ^ ((r & 7) << 4);
        *(ushort4*)((char*)XHhi + r * ROWB + off) = h;
        *(ushort4*)((char*)XHlo + r * ROWB + off) = l;
    }

    f32x4 acc[RB][2];

    #define STAGE_W(WPTR)                                                       \
        for (int idx = tid; idx < 2048; idx += 256) {                           \
            int r = idx >> 4;                                                   \
            int byt = (idx & 15) * 16;                                          \
            *(uint4*)((char*)WS + r * ROWB + (byt ^ ((r & 7) << 4))) =          \
                *(const uint4*)((WPTR) + (size_t)idx * 8);                      \
        }

    #define PASS(WITH_LO)                                                       \
        _Pragma("unroll")                                                       \
        for (int kk = 0; kk < 4; ++kk) {                                        \
            const int kbyte = kk * 64 + kg * 16;                                \
            bf16x8 ah[RB], al[RB];                                              \
            _Pragma("unroll")                                                   \
            for (int rb = 0; rb < RB; ++rb) {                                   \
                int r = 16 * rb + l15;                                          \
                int off = kbyte ^ ((r & 7) << 4);                               \
                ah[rb] = *(const bf16x8*)((const char*)XHhi + r * ROWB + off);  \
                if (WITH_LO)                                                    \
                    al[rb] = *(const bf16x8*)((const char*)XHlo + r * ROWB + off); \
            }                                                                   \
            _Pragma("unroll")                                                   \
            for (int cbi = 0; cbi < 2; ++cbi) {                                 \
                int rw = 16 * (wave + 4 * cbi) + l15;                           \
                int offw = kbyte ^ ((rw & 7) << 4);                             \
                bf16x8 bw = *(const bf16x8*)((const char*)WS + rw * ROWB + offw); \
                _Pragma("unroll")                                               \
                for (int rb = 0; rb < RB; ++rb) {                               \
                    f32x4 t = acc[rb][cbi];                                     \
                    t = __builtin_amdgcn_mfma_f32_16x16x32_bf16(ah[rb], bw, t, 0, 0, 0); \
                    if (WITH_LO)                                                \
                        t = __builtin_amdgcn_mfma_f32_16x16x32_bf16(al[rb], bw, t, 0, 0, 0); \
                    acc[rb][cbi] = t;                                           \
                }                                                               \
            }                                                                   \
        }

    #pragma unroll
    for (int a = 0; a < RB; ++a) { acc[a][0] = (f32x4){0,0,0,0}; acc[a][1] = (f32x4){0,0,0,0}; }
    STAGE_W(W1hi)
    __syncthreads();
    PASS(true)
    __syncthreads();
    STAGE_W(W1lo)
    __syncthreads();
    PASS(false)
    __syncthreads();

    #pragma unroll
    for (int cbi = 0; cbi < 2; ++cbi) {
        int col = 16 * (wave + 4 * cbi) + l15;
        float b1v = b1[col];
        #pragma unroll
        for (int rb = 0; rb < RB; ++rb)
            #pragma unroll
            for (int i = 0; i < 4; ++i) {
                int r = 16 * rb + kg * 4 + i;
                float h = silu_f(acc[rb][cbi][i] + b1v);
                unsigned short hh, hl;
                split_bf(h, hh, hl);
                int off = (2 * col) ^ ((r & 7) << 4);
                *(unsigned short*)((char*)XHhi + r * ROWB + off) = hh;
                *(unsigned short*)((char*)XHlo + r * ROWB + off) = hl;
            }
    }
    #pragma unroll
    for (int a = 0; a < RB; ++a) { acc[a][0] = (f32x4){0,0,0,0}; acc[a][1] = (f32x4){0,0,0,0}; }
    STAGE_W(W2hi)
    __syncthreads();
    PASS(true)
    __syncthreads();
    STAGE_W(W2lo)
    __syncthreads();
    PASS(false)
    #undef PASS
    #undef STAGE_W

    #pragma unroll
    for (int cbi = 0; cbi < 2; ++cbi) {
        int col = 16 * (wave + 4 * cbi) + l15;
        float b2v = b2[col];
        #pragma unroll
        for (int rb = 0; rb < RB; ++rb)
            #pragma unroll
            for (int i = 0; i < 4; ++i) {
                int gr = row0 + 16 * rb + kg * 4 + i;
                if (gr < nrows) {
                    size_t off = (size_t)gr * 128 + col;
                    float val = acc[rb][cbi][i] + b2v;
                    if (RESID) val += (float)Y[off];
                    if constexpr (sizeof(OutT) == 2)
                        Y[off] = __float2bfloat16(val);
                    else
                        Y[off] = val;
                }
            }
    }
}

// ---------------------------------------------------------------------------
// Generic two-stage fp32 MLP (r3-proven), for the K=138 sct layers.
// ---------------------------------------------------------------------------
template<int K, bool PREACT, bool RESID, typename OutT>
__global__ __launch_bounds__(256) void mlp2_kernel(
    const float* __restrict__ X, int ldX,
    const float* __restrict__ W1, const float* __restrict__ b1,
    const float* __restrict__ W2, const float* __restrict__ b2,
    OutT* __restrict__ Y, int ldY, int nrows)
{
    constexpr int NC = (K + 31) / 32;
    constexpr int ROWS = 48;
    constexpr int RR = 6;
    __shared__ float Xs[ROWS * K];
    __shared__ float Hs[ROWS * K];
    const int tid = threadIdx.x;
    const int row0 = blockIdx.x * ROWS;

    for (int idx = tid; idx < ROWS * K; idx += 256) {
        int r = idx / K, c = idx - r * K;
        int gr = row0 + r;
        float x = (gr < nrows) ? X[(size_t)gr * ldX + c] : 0.0f;
        if (PREACT) x = silu_f(x);
        Xs[idx] = x;
    }
    __syncthreads();

    const int cc = tid & 31;
    const int r0 = (tid >> 5) * RR;

    float acc[NC][RR];
    #pragma unroll
    for (int jc = 0; jc < NC; ++jc) {
        int col = cc + 32 * jc;
        float bv = (col < K) ? b1[col] : 0.0f;
        #pragma unroll
        for (int rr = 0; rr < RR; ++rr) acc[jc][rr] = bv;
    }
    for (int k = 0; k < K; ++k) {
        float w[NC];
        #pragma unroll
        for (int jc = 0; jc < NC; ++jc) {
            int col = cc + 32 * jc;
            w[jc] = (col < K) ? W1[k * K + col] : 0.0f;
        }
        float xv[RR];
        #pragma unroll
        for (int rr = 0; rr < RR; ++rr) xv[rr] = Xs[(r0 + rr) * K + k];
        #pragma unroll
        for (int jc = 0; jc < NC; ++jc)
            #pragma unroll
            for (int rr = 0; rr < RR; ++rr)
                acc[jc][rr] = fmaf(xv[rr], w[jc], acc[jc][rr]);
    }
    #pragma unroll
    for (int jc = 0; jc < NC; ++jc) {
        int col = cc + 32 * jc;
        if (col < K) {
            #pragma unroll
            for (int rr = 0; rr < RR; ++rr)
                Hs[(r0 + rr) * K + col] = silu_f(acc[jc][rr]);
        }
    }
    __syncthreads();

    #pragma unroll
    for (int jc = 0; jc < NC; ++jc) {
        int col = cc + 32 * jc;
        float bv = (col < K) ? b2[col] : 0.0f;
        #pragma unroll
        for (int rr = 0; rr < RR; ++rr) acc[jc][rr] = bv;
    }
    for (int k = 0; k < K; ++k) {
        float w[NC];
        #pragma unroll
        for (int jc = 0; jc < NC; ++jc) {
            int col = cc + 32 * jc;
            w[jc] = (col < K) ? W2[k * K + col] : 0.0f;
        }
        float xv[RR];
        #pragma unroll
        for (int rr = 0; rr < RR; ++rr) xv[rr] = Hs[(r0 + rr) * K + k];
        #pragma unroll
        for (int jc = 0; jc < NC; ++jc)
            #pragma unroll
            for (int rr = 0; rr < RR; ++rr)
                acc[jc][rr] = fmaf(xv[rr], w[jc], acc[jc][rr]);
    }
    #pragma unroll
    for (int jc = 0; jc < NC; ++jc) {
        int col = cc + 32 * jc;
        if (col < K) {
            #pragma unroll
            for (int rr = 0; rr < RR; ++rr) {
                int gr = row0 + r0 + rr;
                if (gr < nrows) {
                    size_t off = (size_t)gr * ldY + col;
                    float val = acc[jc][rr];
                    if (RESID) val += (float)Y[off];
                    if constexpr (sizeof(OutT) == 2)
                        Y[off] = __float2bfloat16(val);
                    else
                        Y[off] = val;
                }
            }
        }
    }
}

// ---------------------------------------------------------------------------
// Register-direct MFMA gather, COLUMN-SPLIT (r11) + PREPACKED A (r7):
// 2 waves per node, each owning 4 col-blocks.  No masking: pad slots are
// pre-zeroed (A=0 kills pad columns; js pads -> row 0).
//   T = rbf^T(16x32) @ Phi(32x128) per node;
//   v[n][c] = sum_k dW[k][c]*T[k][c] + db[c]*T_env[c]
// ---------------------------------------------------------------------------
__global__ __launch_bounds__(256) void gather_mfma_kernel(
    const int* __restrict__ peptr,
    const unsigned short* __restrict__ rbfT,   // [EPAD/32][512] A-frag order
    const unsigned short* __restrict__ envs,   // [EPAD] bf16 (pads zero)
    const int* __restrict__ js,                // [EPAD]      (pads zero)
    const unsigned short* __restrict__ phi,    // [N][128] bf16
    const float* __restrict__ distW, const float* __restrict__ distb,
    float* __restrict__ v, int N)
{
    const int wv = blockIdx.x * 4 + (threadIdx.x >> 6);
    const int lane = threadIdx.x & 63;
    const int n = wv >> 1;
    const int h = wv & 1;               // column half: cols 64h .. 64h+63
    if (n >= N) return;
    const int l15 = lane & 15;
    const int lg  = lane >> 4;

    f32x4 acc[4];
    float eac[4];
    #pragma unroll
    for (int cb = 0; cb < 4; ++cb) { acc[cb] = (f32x4){0,0,0,0}; eac[cb] = 0.f; }

    const int p0 = peptr[n], p1 = peptr[n + 1];

    for (int p = p0; p < p1; p += 32) {
        // ---- A-frag: one coalesced 16B/lane read (prepacked) ----
        bf16x8 af = *(const bf16x8*)(rbfT + (size_t)(p >> 5) * 512 + lane * 8);

        // ---- env frag (A2: env in row 0) ----
        bf16x8 a2f = (bf16x8){0,0,0,0,0,0,0,0};
        if (l15 == 0)
            a2f = *(const bf16x8*)(envs + p + 8 * lg);

        // ---- row indices: 2 x int4 coalesced ----
        int4 j03 = *(const int4*)(js + p + 8 * lg);
        int4 j47 = *(const int4*)(js + p + 8 * lg + 4);

        const unsigned short* pb0 = phi + (size_t)j03.x * 128 + 64 * h + l15;
        const unsigned short* pb1 = phi + (size_t)j03.y * 128 + 64 * h + l15;
        const unsigned short* pb2 = phi + (size_t)j03.z * 128 + 64 * h + l15;
        const unsigned short* pb3 = phi + (size_t)j03.w * 128 + 64 * h + l15;
        const unsigned short* pb4 = phi + (size_t)j47.x * 128 + 64 * h + l15;
        const unsigned short* pb5 = phi + (size_t)j47.y * 128 + 64 * h + l15;
        const unsigned short* pb6 = phi + (size_t)j47.z * 128 + 64 * h + l15;
        const unsigned short* pb7 = phi + (size_t)j47.w * 128 + 64 * h + l15;

        #pragma unroll
        for (int cbi = 0; cbi < 4; ++cbi) {
            const int o = cbi * 16;
            unsigned int b0 = (unsigned int)pb0[o] | ((unsigned int)pb1[o] << 16);
            unsigned int b1 = (unsigned int)pb2[o] | ((unsigned int)pb3[o] << 16);
            unsigned int b2 = (unsigned int)pb4[o] | ((unsigned int)pb5[o] << 16);
            unsigned int b3 = (unsigned int)pb6[o] | ((unsigned int)pb7[o] << 16);
            bf16x8 bf = pack8(b0, b1, b2, b3);
            acc[cbi] = __builtin_amdgcn_mfma_f32_16x16x32_bf16(af, bf, acc[cbi], 0, 0, 0);
            f32x4 z = (f32x4){0, 0, 0, 0};
            z = __builtin_amdgcn_mfma_f32_16x16x32_bf16(a2f, bf, z, 0, 0, 0);
            eac[cbi] += z[0];
        }
    }

    // ---- epilogue: dot with dW rows, add db*T_env, reduce across lane-groups
    #pragma unroll
    for (int cbi = 0; cbi < 4; ++cbi) {
        int col = 64 * h + cbi * 16 + l15;
        float part = acc[cbi][0] * distW[(lg * 4 + 0) * 128 + col];
        part = fmaf(acc[cbi][1], distW[(lg * 4 + 1) * 128 + col], part);
        part = fmaf(acc[cbi][2], distW[(lg * 4 + 2) * 128 + col], part);
        part = fmaf(acc[cbi][3], distW[(lg * 4 + 3) * 128 + col], part);
        if (lg == 0) part = fmaf(eac[cbi], distb[col], part);
        part += __shfl_xor(part, 16, 64);
        part += __shfl_xor(part, 32, 64);
        if (lane < 16) v[(size_t)n * 128 + col] = part;
    }
}

// ---------------------------------------------------------------------------
// Fused heads: per node (one wave) compute
//   bbA = silu(silu(S0)@bbaW1+b1)@bbaW2+b2
//   bbT = silu(silu([S0,bbA])@bbtW1+b1)@bbtW2+b2
//   scA = silu(silu(S0)@scaW1+b1)@scaW2+b2
//   scS = concat(S0, scA, 0, 0)
// Replaces 3 head dispatches + concat_sc.
// ---------------------------------------------------------------------------
__global__ __launch_bounds__(256) void fused_heads_kernel(
    const float* __restrict__ S0,
    const float* __restrict__ bbaW1, const float* __restrict__ bbab1,
    const float* __restrict__ bbaW2, const float* __restrict__ bbab2,
    const float* __restrict__ bbtW1, const float* __restrict__ bbtb1,
    const float* __restrict__ bbtW2, const float* __restrict__ bbtb2,
    const float* __restrict__ scaW1, const float* __restrict__ scab1,
    const float* __restrict__ scaW2, const float* __restrict__ scab2,
    float* __restrict__ bbA, float* __restrict__ bbT,
    float* __restrict__ scA, float* __restrict__ scS, int N)
{
    const int wid = threadIdx.x >> 6;
    const int lane = threadIdx.x & 63;
    const int n = blockIdx.x * 4 + wid;
    if (n >= N) return;

    float x0 = S0[(size_t)n * 128 + lane];
    float x1 = S0[(size_t)n * 128 + 64 + lane];
    float s0 = silu_f(x0), s1 = silu_f(x1);

    // ---- bba (M=3, K=128) ----
    float ba[3];
    #pragma unroll
    for (int m = 0; m < 3; ++m)
        ba[m] = fmaf(s0, bbaW1[lane * 3 + m], s1 * bbaW1[(lane + 64) * 3 + m]);
    #pragma unroll
    for (int m = 0; m < 3; ++m)
        #pragma unroll
        for (int off = 32; off > 0; off >>= 1)
            ba[m] += __shfl_xor(ba[m], off, 64);
    float bbo[3];
    {
        float tm[3];
        #pragma unroll
        for (int m = 0; m < 3; ++m) tm[m] = silu_f(ba[m] + bbab1[m]);
        #pragma unroll
        for (int mm = 0; mm < 3; ++mm) {
            float o = bbab2[mm];
            #pragma unroll
            for (int m = 0; m < 3; ++m) o = fmaf(tm[m], bbaW2[m * 3 + mm], o);
            bbo[mm] = o;
        }
    }
    if (lane < 3) {
        float ov = bbo[0];
        if (lane == 1) ov = bbo[1];
        if (lane == 2) ov = bbo[2];
        bbA[(size_t)n * 3 + lane] = ov;
    }

    // ---- bbt (M=3, K=131 = S0 ++ bbA) ----
    float bt[3];
    #pragma unroll
    for (int m = 0; m < 3; ++m)
        bt[m] = fmaf(s0, bbtW1[lane * 3 + m], s1 * bbtW1[(lane + 64) * 3 + m]);
    #pragma unroll
    for (int m = 0; m < 3; ++m)
        #pragma unroll
        for (int off = 32; off > 0; off >>= 1)
            bt[m] += __shfl_xor(bt[m], off, 64);
    #pragma unroll
    for (int m = 0; m < 3; ++m)
        #pragma unroll
        for (int t = 0; t < 3; ++t)
            bt[m] = fmaf(silu_f(bbo[t]), bbtW1[(128 + t) * 3 + m], bt[m]);
    {
        float tm[3], bto[3];
        #pragma unroll
        for (int m = 0; m < 3; ++m) tm[m] = silu_f(bt[m] + bbtb1[m]);
        #pragma unroll
        for (int mm = 0; mm < 3; ++mm) {
            float o = bbtb2[mm];
            #pragma unroll
            for (int m = 0; m < 3; ++m) o = fmaf(tm[m], bbtW2[m * 3 + mm], o);
            bto[mm] = o;
        }
        if (lane < 3) {
            float ov = bto[0];
            if (lane == 1) ov = bto[1];
            if (lane == 2) ov = bto[2];
            bbT[(size_t)n * 3 + lane] = ov;
        }
    }

    // ---- sca (M=10, K=128) ----
    float sa[10];
    #pragma unroll
    for (int m = 0; m < 10; ++m)
        sa[m] = fmaf(s0, scaW1[lane * 10 + m], s1 * scaW1[(lane + 64) * 10 + m]);
    #pragma unroll
    for (int m = 0; m < 10; ++m)
        #pragma unroll
        for (int off = 32; off > 0; off >>= 1)
            sa[m] += __shfl_xor(sa[m], off, 64);
    float sco[10];
    {
        float tm[10];
        #pragma unroll
        for (int m = 0; m < 10; ++m) tm[m] = silu_f(sa[m] + scab1[m]);
        #pragma unroll
        for (int mm = 0; mm < 10; ++mm) {
            float o = scab2[mm];
            #pragma unroll
            for (int m = 0; m < 10; ++m) o = fmaf(tm[m], scaW2[m * 10 + mm], o);
            sco[mm] = o;
        }
    }
    float scv = sco[0];
    #pragma unroll
    for (int m = 1; m < 10; ++m)
        if (lane == m) scv = sco[m];
    if (lane < 10) scA[(size_t)n * 10 + lane] = scv;

    // ---- scS = concat(S0, scA, pad) ----
    scS[(size_t)n * 140 + lane] = x0;
    scS[(size_t)n * 140 + 64 + lane] = x1;
    if (lane < 12) scS[(size_t)n * 140 + 128 + lane] = (lane < 10) ? scv : 0.0f;
}

// ---------------------------------------------------------------------------
// Small head: out = silu( silu(x) @ W1 + b1 ) @ W2 + b2   (final linear)
// ---------------------------------------------------------------------------
template<int M>
__global__ __launch_bounds__(256) void head_kernel(
    const float* __restrict__ X, int ldX, int K1,
    const float* __restrict__ X2, int ldX2, int K2,
    const float* __restrict__ W1, const float* __restrict__ b1,
    const float* __restrict__ W2, const float* __restrict__ b2,
    float* __restrict__ out, int ldOut, int nrows)
{
    const int wid = threadIdx.x >> 6;
    const int lane = threadIdx.x & 63;
    const int n = blockIdx.x * 4 + wid;
    if (n >= nrows) return;
    const int K = K1 + K2;
    float sx[3];
    #pragma unroll
    for (int t = 0; t < 3; ++t) {
        int k = lane + 64 * t;
        float v = 0.0f;
        if (k < K1) v = X[(size_t)n * ldX + k];
        else if (k < K) v = X2[(size_t)n * ldX2 + (k - K1)];
        sx[t] = (k < K) ? silu_f(v) : 0.0f;
    }
    float acc[M];
    #pragma unroll
    for (int m = 0; m < M; ++m) {
        float a = 0.0f;
        #pragma unroll
        for (int t = 0; t < 3; ++t) {
            int k = lane + 64 * t;
            if (k < K) a = fmaf(sx[t], W1[k * M + m], a);
        }
        acc[m] = a;
    }
    #pragma unroll
    for (int m = 0; m < M; ++m) {
        #pragma unroll
        for (int off = 32; off > 0; off >>= 1)
            acc[m] += __shfl_xor(acc[m], off, 64);
    }
    float tm[M];
    #pragma unroll
    for (int m = 0; m < M; ++m) tm[m] = silu_f(acc[m] + b1[m]);
    if (lane < M) {
        float o = b2[lane];
        #pragma unroll
        for (int m = 0; m < M; ++m) o = fmaf(tm[m], W2[m * M + lane], o);
        out[(size_t)n * ldOut + lane] = o;
    }
}

// ---------------------------------------------------------------------------
// Output assembly: out[N][13][3]
// ---------------------------------------------------------------------------
__global__ __launch_bounds__(256) void assemble_kernel(
    const int* __restrict__ z,
    const float* __restrict__ bbde, const float* __restrict__ scde,
    const float* __restrict__ bbA, const float* __restrict__ bbT,
    const float* __restrict__ scA, const float* __restrict__ scT,
    float* __restrict__ out, int N)
{
    int idx = blockIdx.x * 256 + threadIdx.x;
    if (idx >= N * 39) return;
    int n = idx / 39;
    int s = idx - n * 39;
    int row = s / 3;
    int col = s - row * 3;
    float val;
    if (row < 3) {
        if (col == 0)      val = bbde[z[n] * 3 + row];
        else if (col == 1) val = bbA[n * 3 + row];
        else               val = bbT[n * 3 + row];
    } else {
        int r = row - 3;
        if (col == 0)      val = scde[z[n] * 10 + r];
        else if (col == 1) val = scA[n * 10 + r];
        else               val = scT[n * 10 + r];
    }
    out[idx] = val;
}

extern "C" void kernel_launch(void* const* d_in, const int* in_sizes, int n_in,
                              void* d_out, int out_size, void* d_ws, size_t ws_size,
                              hipStream_t stream)
{
    const int*   cg_z        = (const int*)d_in[0];
    const float* cg_xyz      = (const float*)d_in[1];
    const int*   nbr         = (const int*)d_in[2];
    // d_in[3] = mapping (unused by reference)
    const float* S_in        = (const float*)d_in[4];
    const float* res_embed   = (const float*)d_in[5];
    const float* msg_W1      = (const float*)d_in[6];
    const float* msg_b1      = (const float*)d_in[7];
    const float* msg_W2      = (const float*)d_in[8];
    const float* msg_b2      = (const float*)d_in[9];
    const float* dist_W      = (const float*)d_in[10];
    const float* dist_b      = (const float*)d_in[11];
    const float* dense_W1    = (const float*)d_in[12];
    const float* dense_b1    = (const float*)d_in[13];
    const float* dense_W2    = (const float*)d_in[14];
    const float* dense_b2    = (const float*)d_in[15];
    const float* bb_dist_emb = (const float*)d_in[16];
    const float* sc_dist_emb = (const float*)d_in[17];
    const float* bba_W1      = (const float*)d_in[18];
    const float* bba_b1      = (const float*)d_in[19];
    const float* bba_W2      = (const float*)d_in[20];
    const float* bba_b2      = (const float*)d_in[21];
    const float* sca_W1      = (const float*)d_in[22];
    const float* sca_b1      = (const float*)d_in[23];
    const float* sca_W2      = (const float*)d_in[24];
    const float* sca_b2      = (const float*)d_in[25];
    const float* bbt_W1      = (const float*)d_in[26];
    const float* bbt_b1      = (const float*)d_in[27];
    const float* bbt_W2      = (const float*)d_in[28];
    const float* bbt_b2      = (const float*)d_in[29];
    const float* sct_W1      = (const float*)d_in[30];
    const float* sct_b1      = (const float*)d_in[31];
    const float* sct_W2      = (const float*)d_in[32];
    const float* sct_b2      = (const float*)d_in[33];
    const float* ft_W1       = (const float*)d_in[34];
    const float* ft_b1       = (const float*)d_in[35];
    const float* ft_W2       = (const float*)d_in[36];
    const float* ft_b2       = (const float*)d_in[37];

    const int N = in_sizes[0];
    const int E = in_sizes[2] / 2;
    const int EPAD = ((E + 31 * N) / 32) * 32 + 32;   // padded-edge upper bound

    unsigned short* WB   = (unsigned short*)d_ws;                      // 24*WSLOT
    unsigned short* rbfT = WB + (size_t)24 * WSLOT;                    // EPAD*16 (A-frag order)
    unsigned short* envs = rbfT + (size_t)EPAD * 16;                   // EPAD
    int*            js   = (int*)(envs + (size_t)EPAD);                // EPAD
    float* ws   = (float*)(js + (size_t)EPAD);
    float* S0   = ws;  ws += (size_t)N * 128;
    float* V    = ws;  ws += (size_t)N * 128;
    float* scS  = ws;  ws += (size_t)N * 140;
    float* bbA  = ws;  ws += (size_t)N * 3;
    float* bbT  = ws;  ws += (size_t)N * 3;
    float* scA  = ws;  ws += (size_t)N * 10;
    float* scT  = ws;  ws += (size_t)N * 10;
    __hip_bfloat16* PHI = (__hip_bfloat16*)ws;  ws += (size_t)N * 64;  // N*128 bf16
    int* peptr  = (int*)ws;  ws = (float*)((int*)ws + (N + 1));
    int* counts = (int*)ws;  ws = (float*)((int*)ws + N);
    int* cursor = (int*)ws;  ws = (float*)((int*)ws + N);

    // Zero padded edge region (rbfT|envs|js contiguous) + counts/cursor.
    (void)hipMemsetAsync(rbfT, 0, (size_t)EPAD * 38, stream);
    (void)hipMemsetAsync(counts, 0, (size_t)2 * N * sizeof(int), stream);

    prep_weights_kernel<<<dim3(64, 12), 256, 0, stream>>>(
        msg_W1, msg_W2, dense_W1, dense_W2, WB);

    hist_kernel<<<DIV_UP(E, 256), 256, 0, stream>>>(nbr, counts, E);
    scan_kernel<<<1, 1024, 0, stream>>>(counts, peptr, N);
    geom_scatter_kernel<<<DIV_UP(E, 256), 256, 0, stream>>>(
        nbr, cg_xyz, peptr, cursor, rbfT, envs, js, E);

    concat_s_kernel<<<DIV_UP(N * 128, 256), 256, 0, stream>>>(S_in, res_embed, cg_z, S0, N);

    #define WHI(kind, conv) (WB + (size_t)(2 * ((kind) * 3 + (conv))) * WSLOT)
    #define WLO(kind, conv) (WB + (size_t)(2 * ((kind) * 3 + (conv)) + 1) * WSLOT)

    for (int i = 0; i < 3; ++i) {
        mlp2_mfma_kernel<48, false, false, __hip_bfloat16>
            <<<DIV_UP(N, 48), 256, 0, stream>>>(
            S0, WHI(0, i), WLO(0, i), msg_b1 + i * 128,
            WHI(1, i), WLO(1, i), msg_b2 + i * 128, PHI, N);
        gather_mfma_kernel<<<DIV_UP(2 * N, 4), 256, 0, stream>>>(
            peptr, rbfT, envs, js, (const unsigned short*)PHI,
            dist_W + (size_t)i * 16 * 128, dist_b + i * 128, V, N);
        mlp2_mfma_kernel<48, true, true, float>
            <<<DIV_UP(N, 48), 256, 0, stream>>>(
            V, WHI(2, i), WLO(2, i), dense_b1 + i * 128,
            WHI(3, i), WLO(3, i), dense_b2 + i * 128, S0, N);
    }

    fused_heads_kernel<<<DIV_UP(N, 4), 256, 0, stream>>>(
        S0,
        bba_W1, bba_b1, bba_W2, bba_b2,
        bbt_W1, bbt_b1, bbt_W2, bbt_b2,
        sca_W1, sca_b1, sca_W2, sca_b2,
        bbA, bbT, scA, scS, N);

    for (int i = 0; i < 3; ++i) {
        mlp2_kernel<138, true, true, float><<<DIV_UP(N, 48), 256, 0, stream>>>(
            scS, 140, sct_W1 + (size_t)i * 138 * 138, sct_b1 + i * 138,
            sct_W2 + (size_t)i * 138 * 138, sct_b2 + i * 138, scS, 140, N);
    }
    head_kernel<10><<<DIV_UP(N, 4), 256, 0, stream>>>(
        scS, 140, 138, scS, 0, 0, ft_W1, ft_b1, ft_W2, ft_b2, scT, 10, N);

    assemble_kernel<<<DIV_UP(N * 39, 256), 256, 0, stream>>>(
        cg_z, bb_dist_emb, sc_dist_emb, bbA, bbT, scA, scT, (float*)d_out, N);

    #undef WHI
    #undef WLO
}